// Round 2
// baseline (3903.468 us; speedup 1.0000x reference)
//
#include <hip/hip_runtime.h>
#include <hip/hip_bf16.h>
#include <cstdint>
#include <cstddef>

#define N_NODES 100000
#define N_EDGES 300000
#define N_GRAPHS 2000
#define HID 256
#define INDIM 82

// ---------------- degree / dinv ----------------
__global__ void k_deg_init(float* deg) {
    int i = blockIdx.x * 256 + threadIdx.x;
    if (i < N_NODES) deg[i] = 1.0f;  // self-loop
}

__global__ void k_deg_acc(const int* __restrict__ ei, float* deg) {
    int e = blockIdx.x * 256 + threadIdx.x;
    if (e < N_EDGES) atomicAdd(&deg[ei[N_EDGES + e]], 1.0f);
}

__global__ void k_deg_fin(float* deg) {
    int i = blockIdx.x * 256 + threadIdx.x;
    if (i < N_NODES) deg[i] = rsqrtf(deg[i]);
}

// ---------------- f32 tiled GEMM: C[N,256] = act(A[N,K]) @ W[K,256] ----------------
// BM=64, BN=64, BK=16; 256 threads as 16x16, each computes 4x4.
template <int K, bool RELU_IN>
__global__ __launch_bounds__(256) void k_gemm(const float* __restrict__ A,
                                              const float* __restrict__ Wm,
                                              float* __restrict__ C) {
    constexpr int BM = 64, BN = 64, BK = 16;
    constexpr int AS_STRIDE = 68;  // pad to kill LDS write conflicts, keep 16B align
    __shared__ __align__(16) float As[BK * AS_STRIDE];
    __shared__ __align__(16) float Ws[BK * BN];

    const int tid = threadIdx.x;
    const int tx = tid & 15;   // col group
    const int ty = tid >> 4;   // row group
    const int row0 = blockIdx.y * BM;
    const int col0 = blockIdx.x * BN;

    float acc[4][4] = {};

    for (int k0 = 0; k0 < K; k0 += BK) {
        // Stage A: As[k*AS_STRIDE + m] = act(A[(row0+m)*K + k0+k])
#pragma unroll
        for (int t = tid; t < BM * BK; t += 256) {
            int m = t >> 4;
            int k = t & 15;
            int row = row0 + m;
            float v = 0.0f;
            if (row < N_NODES && (k0 + k) < K) v = A[(size_t)row * K + k0 + k];
            if (RELU_IN) v = fmaxf(v, 0.0f);
            As[k * AS_STRIDE + m] = v;
        }
        // Stage W: Ws[k*BN + n] = W[(k0+k)*256 + col0+n]
#pragma unroll
        for (int t = tid; t < BK * BN; t += 256) {
            int k = t >> 6;
            int n = t & 63;
            float v = ((k0 + k) < K) ? Wm[(size_t)(k0 + k) * HID + col0 + n] : 0.0f;
            Ws[k * BN + n] = v;
        }
        __syncthreads();

#pragma unroll
        for (int k = 0; k < BK; ++k) {
            float4 a4 = *reinterpret_cast<const float4*>(&As[k * AS_STRIDE + ty * 4]);
            float4 b4 = *reinterpret_cast<const float4*>(&Ws[k * BN + tx * 4]);
            float a[4] = {a4.x, a4.y, a4.z, a4.w};
            float b[4] = {b4.x, b4.y, b4.z, b4.w};
#pragma unroll
            for (int i = 0; i < 4; ++i)
#pragma unroll
                for (int j = 0; j < 4; ++j) acc[i][j] = fmaf(a[i], b[j], acc[i][j]);
        }
        __syncthreads();
    }

#pragma unroll
    for (int i = 0; i < 4; ++i) {
        int row = row0 + ty * 4 + i;
        if (row < N_NODES) {
            float4 v = {acc[i][0], acc[i][1], acc[i][2], acc[i][3]};
            *reinterpret_cast<float4*>(&C[(size_t)row * HID + col0 + tx * 4]) = v;
        }
    }
}

// ---------------- init: out[i,:] = tmp[i,:] * dinv[i]^2 + b ----------------
__global__ void k_init_agg(const float* __restrict__ tmp, const float* __restrict__ dinv,
                           const float* __restrict__ bias, float* __restrict__ out) {
    int node = blockIdx.x * 4 + (threadIdx.x >> 6);
    if (node >= N_NODES) return;
    int lane = threadIdx.x & 63;
    float di = dinv[node];
    float s = di * di;
    float4 v = *reinterpret_cast<const float4*>(&tmp[(size_t)node * HID + lane * 4]);
    float4 bb = *reinterpret_cast<const float4*>(&bias[lane * 4]);
    float4 o = {v.x * s + bb.x, v.y * s + bb.y, v.z * s + bb.z, v.w * s + bb.w};
    *reinterpret_cast<float4*>(&out[(size_t)node * HID + lane * 4]) = o;
}

// ---------------- edge scatter: out[dst,:] += tmp[src,:] * dinv[src]*dinv[dst] ----------------
__global__ void k_scatter(const int* __restrict__ ei, const float* __restrict__ tmp,
                          const float* __restrict__ dinv, float* __restrict__ out) {
    int e = blockIdx.x * 4 + (threadIdx.x >> 6);
    if (e >= N_EDGES) return;
    int lane = threadIdx.x & 63;
    int s = ei[e];
    int d = ei[N_EDGES + e];
    float norm = dinv[s] * dinv[d];
    float4 v = *reinterpret_cast<const float4*>(&tmp[(size_t)s * HID + lane * 4]);
    float* o = &out[(size_t)d * HID + (size_t)lane * 4];
    atomicAdd(o + 0, v.x * norm);
    atomicAdd(o + 1, v.y * norm);
    atomicAdd(o + 2, v.z * norm);
    atomicAdd(o + 3, v.w * norm);
}

// ---------------- pooling: out[g,:] = max over nodes in g of relu(h[i,:]) ----------------
__global__ void k_pool_init(float* out) {
    int i = blockIdx.x * 256 + threadIdx.x;
    if (i < N_GRAPHS * HID) out[i] = 0.0f;
}

__global__ void k_pool(const float* __restrict__ h, const int* __restrict__ batch,
                       float* __restrict__ out) {
    int node = blockIdx.x * 4 + (threadIdx.x >> 6);
    if (node >= N_NODES) return;
    int lane = threadIdx.x & 63;
    int g = batch[node];
    float4 v = *reinterpret_cast<const float4*>(&h[(size_t)node * HID + lane * 4]);
    // relu fused: values >= 0, so int ordering == float ordering for atomicMax
    int* o = reinterpret_cast<int*>(&out[(size_t)g * HID + (size_t)lane * 4]);
    atomicMax(o + 0, __float_as_int(fmaxf(v.x, 0.0f)));
    atomicMax(o + 1, __float_as_int(fmaxf(v.y, 0.0f)));
    atomicMax(o + 2, __float_as_int(fmaxf(v.z, 0.0f)));
    atomicMax(o + 3, __float_as_int(fmaxf(v.w, 0.0f)));
}

extern "C" void kernel_launch(void* const* d_in, const int* in_sizes, int n_in,
                              void* d_out, int out_size, void* d_ws, size_t ws_size,
                              hipStream_t stream) {
    const float* x = (const float*)d_in[0];
    const int* ei = (const int*)d_in[1];      // int32 per harness contract, [2, E] flat
    const int* batch = (const int*)d_in[2];   // int32
    // d_in[3] = num_graphs scalar (2000, hardcoded)
    const float* W1 = (const float*)d_in[4];
    const float* b1 = (const float*)d_in[5];
    const float* W2 = (const float*)d_in[6];
    const float* b2 = (const float*)d_in[7];
    const float* W3 = (const float*)d_in[8];
    const float* b3 = (const float*)d_in[9];
    float* out = (float*)d_out;

    // workspace layout (f32): dinv 512KB | tmp 102.4MB | h 102.4MB
    float* dinv = (float*)d_ws;
    float* tmp = dinv + 128 * 1024;               // xW buffer [N, 256]
    float* h = tmp + (size_t)N_NODES * HID;       // aggregated buffer [N, 256]

    const int nblk_nodes = (N_NODES + 255) / 256;
    const int nblk_edges = (N_EDGES + 255) / 256;
    const int nblk_rows4 = (N_NODES + 3) / 4;     // 1 wave per node
    const int nblk_edge4 = (N_EDGES + 3) / 4;     // 1 wave per edge

    // degree / dinv
    k_deg_init<<<nblk_nodes, 256, 0, stream>>>(dinv);
    k_deg_acc<<<nblk_edges, 256, 0, stream>>>(ei, dinv);
    k_deg_fin<<<nblk_nodes, 256, 0, stream>>>(dinv);

    dim3 ggrid(HID / 64, (N_NODES + 63) / 64);

    // ---- layer 1: x[N,82] @ W1 ----
    k_gemm<INDIM, false><<<ggrid, 256, 0, stream>>>(x, W1, tmp);
    k_init_agg<<<nblk_rows4, 256, 0, stream>>>(tmp, dinv, b1, h);
    k_scatter<<<nblk_edge4, 256, 0, stream>>>(ei, tmp, dinv, h);

    // ---- layer 2: relu(h) @ W2 ----
    k_gemm<HID, true><<<ggrid, 256, 0, stream>>>(h, W2, tmp);
    k_init_agg<<<nblk_rows4, 256, 0, stream>>>(tmp, dinv, b2, h);
    k_scatter<<<nblk_edge4, 256, 0, stream>>>(ei, tmp, dinv, h);

    // ---- layer 3: relu(h) @ W3 ----
    k_gemm<HID, true><<<ggrid, 256, 0, stream>>>(h, W3, tmp);
    k_init_agg<<<nblk_rows4, 256, 0, stream>>>(tmp, dinv, b3, h);
    k_scatter<<<nblk_edge4, 256, 0, stream>>>(ei, tmp, dinv, h);

    // ---- pool: segment_max(relu(h), batch) ----
    k_pool_init<<<(N_GRAPHS * HID + 255) / 256, 256, 0, stream>>>(out);
    k_pool<<<nblk_rows4, 256, 0, stream>>>(h, batch, out);
}

// Round 3
// 1061.727 us; speedup vs baseline: 3.6765x; 3.6765x over previous
//
#include <hip/hip_runtime.h>
#include <hip/hip_bf16.h>
#include <cstdint>
#include <cstddef>

#define N_NODES 100000
#define N_EDGES 300000
#define N_GRAPHS 2000
#define HID 256
#define INDIM 82
#define SCAN_CHUNK 2048
#define NBLK_SCAN ((N_NODES + SCAN_CHUNK - 1) / SCAN_CHUNK)  // 49

// ---------------- degree counting ----------------
__global__ void k_cnt_init(int* cnt) {
    int i = blockIdx.x * 256 + threadIdx.x;
    if (i < N_NODES) cnt[i] = 0;
}

__global__ void k_cnt_acc(const int* __restrict__ ei, int* cnt) {
    int e = blockIdx.x * 256 + threadIdx.x;
    if (e < N_EDGES) atomicAdd(&cnt[ei[N_EDGES + e]], 1);
}

__global__ void k_dinv(const int* __restrict__ cnt, float* dinv) {
    int i = blockIdx.x * 256 + threadIdx.x;
    if (i < N_NODES) dinv[i] = rsqrtf((float)cnt[i] + 1.0f);  // +1 self-loop
}

// ---------------- exclusive prefix sum over cnt -> off ----------------
// 256 threads x 8 elements = 2048 per block
__global__ __launch_bounds__(256) void k_scan1(const int* __restrict__ cnt, int* __restrict__ off,
                                               int* __restrict__ partial) {
    __shared__ int sdata[256];
    const int base = blockIdx.x * SCAN_CHUNK;
    const int t = threadIdx.x;
    int v[8];
    int s = 0;
#pragma unroll
    for (int i = 0; i < 8; ++i) {
        int idx = base + t * 8 + i;
        v[i] = (idx < N_NODES) ? cnt[idx] : 0;
        s += v[i];
    }
    sdata[t] = s;
    __syncthreads();
    // Hillis-Steele inclusive scan
    for (int d = 1; d < 256; d <<= 1) {
        int x = (t >= d) ? sdata[t - d] : 0;
        __syncthreads();
        sdata[t] += x;
        __syncthreads();
    }
    int run = sdata[t] - s;  // exclusive prefix for this thread's chunk
#pragma unroll
    for (int i = 0; i < 8; ++i) {
        int idx = base + t * 8 + i;
        if (idx < N_NODES) off[idx] = run;
        run += v[i];
    }
    if (t == 255) partial[blockIdx.x] = sdata[255];
}

__global__ void k_scan2(int* partial) {
    if (threadIdx.x == 0 && blockIdx.x == 0) {
        int run = 0;
        for (int i = 0; i < NBLK_SCAN; ++i) {
            int v = partial[i];
            partial[i] = run;
            run += v;
        }
    }
}

__global__ void k_scan3(int* __restrict__ off, const int* __restrict__ partial,
                        int* __restrict__ cur) {
    int i = blockIdx.x * 256 + threadIdx.x;
    if (i < N_NODES) {
        int o = off[i] + partial[i >> 11];  // 2048 elems per scan block
        off[i] = o;
        cur[i] = o;
    }
}

// ---------------- CSR fill: csr_src[pos] = src, bucketed by dst ----------------
__global__ void k_fill(const int* __restrict__ ei, int* cur, int* __restrict__ csr_src) {
    int e = blockIdx.x * 256 + threadIdx.x;
    if (e < N_EDGES) {
        int s = ei[e];
        int d = ei[N_EDGES + e];
        int pos = atomicAdd(&cur[d], 1);
        csr_src[pos] = s;
    }
}

// ---------------- f32 tiled GEMM: C[N,256] = act(A[N,K]) @ W[K,256] ----------------
template <int K, bool RELU_IN>
__global__ __launch_bounds__(256) void k_gemm(const float* __restrict__ A,
                                              const float* __restrict__ Wm,
                                              float* __restrict__ C) {
    constexpr int BM = 64, BN = 64, BK = 16;
    constexpr int AS_STRIDE = 68;
    __shared__ __align__(16) float As[BK * AS_STRIDE];
    __shared__ __align__(16) float Ws[BK * BN];

    const int tid = threadIdx.x;
    const int tx = tid & 15;
    const int ty = tid >> 4;
    const int row0 = blockIdx.y * BM;
    const int col0 = blockIdx.x * BN;

    float acc[4][4] = {};

    for (int k0 = 0; k0 < K; k0 += BK) {
#pragma unroll
        for (int t = tid; t < BM * BK; t += 256) {
            int m = t >> 4;
            int k = t & 15;
            int row = row0 + m;
            float v = 0.0f;
            if (row < N_NODES && (k0 + k) < K) v = A[(size_t)row * K + k0 + k];
            if (RELU_IN) v = fmaxf(v, 0.0f);
            As[k * AS_STRIDE + m] = v;
        }
#pragma unroll
        for (int t = tid; t < BK * BN; t += 256) {
            int k = t >> 6;
            int n = t & 63;
            float v = ((k0 + k) < K) ? Wm[(size_t)(k0 + k) * HID + col0 + n] : 0.0f;
            Ws[k * BN + n] = v;
        }
        __syncthreads();

#pragma unroll
        for (int k = 0; k < BK; ++k) {
            float4 a4 = *reinterpret_cast<const float4*>(&As[k * AS_STRIDE + ty * 4]);
            float4 b4 = *reinterpret_cast<const float4*>(&Ws[k * BN + tx * 4]);
            float a[4] = {a4.x, a4.y, a4.z, a4.w};
            float b[4] = {b4.x, b4.y, b4.z, b4.w};
#pragma unroll
            for (int i = 0; i < 4; ++i)
#pragma unroll
                for (int j = 0; j < 4; ++j) acc[i][j] = fmaf(a[i], b[j], acc[i][j]);
        }
        __syncthreads();
    }

#pragma unroll
    for (int i = 0; i < 4; ++i) {
        int row = row0 + ty * 4 + i;
        if (row < N_NODES) {
            float4 v = {acc[i][0], acc[i][1], acc[i][2], acc[i][3]};
            *reinterpret_cast<float4*>(&C[(size_t)row * HID + col0 + tx * 4]) = v;
        }
    }
}

// ---------------- fused aggregate: out[i] = b + dinv[i]^2*tmp[i] + sum_e norm*tmp[src] ----------------
__global__ void k_aggregate(const float* __restrict__ tmp, const float* __restrict__ dinv,
                            const int* __restrict__ off, const int* __restrict__ cnt,
                            const int* __restrict__ csr_src, const float* __restrict__ bias,
                            float* __restrict__ out) {
    int node = blockIdx.x * 4 + (threadIdx.x >> 6);
    if (node >= N_NODES) return;
    int lane = threadIdx.x & 63;
    float di = dinv[node];
    float s2 = di * di;
    float4 v = *reinterpret_cast<const float4*>(&tmp[(size_t)node * HID + lane * 4]);
    float4 bb = *reinterpret_cast<const float4*>(&bias[lane * 4]);
    float4 acc = {v.x * s2 + bb.x, v.y * s2 + bb.y, v.z * s2 + bb.z, v.w * s2 + bb.w};

    int o0 = off[node];
    int n = cnt[node];
    for (int j = 0; j < n; ++j) {
        int s = csr_src[o0 + j];
        float norm = dinv[s] * di;
        float4 u = *reinterpret_cast<const float4*>(&tmp[(size_t)s * HID + lane * 4]);
        acc.x = fmaf(norm, u.x, acc.x);
        acc.y = fmaf(norm, u.y, acc.y);
        acc.z = fmaf(norm, u.z, acc.z);
        acc.w = fmaf(norm, u.w, acc.w);
    }
    *reinterpret_cast<float4*>(&out[(size_t)node * HID + lane * 4]) = acc;
}

// ---------------- pooling: out[g,:] = max over nodes in g of relu(h[i,:]) ----------------
__global__ void k_pool_init(float* out) {
    int i = blockIdx.x * 256 + threadIdx.x;
    if (i < N_GRAPHS * HID) out[i] = 0.0f;
}

__global__ void k_pool(const float* __restrict__ h, const int* __restrict__ batch,
                       float* __restrict__ out) {
    int node = blockIdx.x * 4 + (threadIdx.x >> 6);
    if (node >= N_NODES) return;
    int lane = threadIdx.x & 63;
    int g = batch[node];
    float4 v = *reinterpret_cast<const float4*>(&h[(size_t)node * HID + lane * 4]);
    int* o = reinterpret_cast<int*>(&out[(size_t)g * HID + (size_t)lane * 4]);
    atomicMax(o + 0, __float_as_int(fmaxf(v.x, 0.0f)));
    atomicMax(o + 1, __float_as_int(fmaxf(v.y, 0.0f)));
    atomicMax(o + 2, __float_as_int(fmaxf(v.z, 0.0f)));
    atomicMax(o + 3, __float_as_int(fmaxf(v.w, 0.0f)));
}

extern "C" void kernel_launch(void* const* d_in, const int* in_sizes, int n_in,
                              void* d_out, int out_size, void* d_ws, size_t ws_size,
                              hipStream_t stream) {
    const float* x = (const float*)d_in[0];
    const int* ei = (const int*)d_in[1];
    const int* batch = (const int*)d_in[2];
    const float* W1 = (const float*)d_in[4];
    const float* b1 = (const float*)d_in[5];
    const float* W2 = (const float*)d_in[6];
    const float* b2 = (const float*)d_in[7];
    const float* W3 = (const float*)d_in[8];
    const float* b3 = (const float*)d_in[9];
    float* out = (float*)d_out;

    // workspace layout
    char* ws = (char*)d_ws;
    float* dinv = (float*)ws;                        // 512 KB reserved
    int* cnt = (int*)(ws + 512 * 1024);              // 512 KB
    int* off = (int*)(ws + 1024 * 1024);             // 512 KB
    int* cur = (int*)(ws + 1536 * 1024);             // 512 KB
    int* part = (int*)(ws + 2048 * 1024);            // 64 KB reserved
    int* csr_src = (int*)(ws + 2112 * 1024);         // 2 MB reserved
    float* tmp = (float*)(ws + 4160 * 1024);         // 102.4 MB
    float* h = tmp + (size_t)N_NODES * HID;          // 102.4 MB

    const int nblk_nodes = (N_NODES + 255) / 256;
    const int nblk_edges = (N_EDGES + 255) / 256;
    const int nblk_rows4 = (N_NODES + 3) / 4;

    // ---- CSR build + dinv ----
    k_cnt_init<<<nblk_nodes, 256, 0, stream>>>(cnt);
    k_cnt_acc<<<nblk_edges, 256, 0, stream>>>(ei, cnt);
    k_dinv<<<nblk_nodes, 256, 0, stream>>>(cnt, dinv);
    k_scan1<<<NBLK_SCAN, 256, 0, stream>>>(cnt, off, part);
    k_scan2<<<1, 64, 0, stream>>>(part);
    k_scan3<<<nblk_nodes, 256, 0, stream>>>(off, part, cur);
    k_fill<<<nblk_edges, 256, 0, stream>>>(ei, cur, csr_src);

    dim3 ggrid(HID / 64, (N_NODES + 63) / 64);

    // ---- layer 1 ----
    k_gemm<INDIM, false><<<ggrid, 256, 0, stream>>>(x, W1, tmp);
    k_aggregate<<<nblk_rows4, 256, 0, stream>>>(tmp, dinv, off, cnt, csr_src, b1, h);

    // ---- layer 2 ----
    k_gemm<HID, true><<<ggrid, 256, 0, stream>>>(h, W2, tmp);
    k_aggregate<<<nblk_rows4, 256, 0, stream>>>(tmp, dinv, off, cnt, csr_src, b2, h);

    // ---- layer 3 ----
    k_gemm<HID, true><<<ggrid, 256, 0, stream>>>(h, W3, tmp);
    k_aggregate<<<nblk_rows4, 256, 0, stream>>>(tmp, dinv, off, cnt, csr_src, b3, h);

    // ---- pool ----
    k_pool_init<<<(N_GRAPHS * HID + 255) / 256, 256, 0, stream>>>(out);
    k_pool<<<nblk_rows4, 256, 0, stream>>>(h, batch, out);
}

// Round 4
// 510.687 us; speedup vs baseline: 7.6436x; 2.0790x over previous
//
#include <hip/hip_runtime.h>
#include <cstdint>
#include <cstddef>

#define N_NODES 100000
#define N_EDGES 300000
#define N_GRAPHS 2000
#define HID 256
#define INDIM 82
#define K1PAD 96
#define SCAN_CHUNK 2048
#define NBLK_SCAN ((N_NODES + SCAN_CHUNK - 1) / SCAN_CHUNK)  // 49

typedef __bf16 bf16x8 __attribute__((ext_vector_type(8)));
typedef float f32x4 __attribute__((ext_vector_type(4)));

__device__ __forceinline__ unsigned short f2bf(float f) {
    unsigned int u = __float_as_uint(f);
    u = (u + 0x7fffu + ((u >> 16) & 1u)) >> 16;  // RNE
    return (unsigned short)u;
}
__device__ __forceinline__ float bf2f(unsigned short s) {
    return __uint_as_float(((unsigned int)s) << 16);
}

// ---------------- degree counting / dinv ----------------
__global__ void k_cnt_init(int* cnt) {
    int i = blockIdx.x * 256 + threadIdx.x;
    if (i < N_NODES) cnt[i] = 0;
}

__global__ void k_cnt_acc(const int* __restrict__ ei, int* cnt) {
    int e = blockIdx.x * 256 + threadIdx.x;
    if (e < N_EDGES) atomicAdd(&cnt[ei[N_EDGES + e]], 1);
}

__global__ void k_dinv(const int* __restrict__ cnt, float* dinv) {
    int i = blockIdx.x * 256 + threadIdx.x;
    if (i < N_NODES) dinv[i] = rsqrtf((float)cnt[i] + 1.0f);
}

// ---------------- exclusive prefix sum ----------------
__global__ __launch_bounds__(256) void k_scan1(const int* __restrict__ cnt, int* __restrict__ off,
                                               int* __restrict__ partial) {
    __shared__ int sdata[256];
    const int base = blockIdx.x * SCAN_CHUNK;
    const int t = threadIdx.x;
    int v[8];
    int s = 0;
#pragma unroll
    for (int i = 0; i < 8; ++i) {
        int idx = base + t * 8 + i;
        v[i] = (idx < N_NODES) ? cnt[idx] : 0;
        s += v[i];
    }
    sdata[t] = s;
    __syncthreads();
    for (int d = 1; d < 256; d <<= 1) {
        int x = (t >= d) ? sdata[t - d] : 0;
        __syncthreads();
        sdata[t] += x;
        __syncthreads();
    }
    int run = sdata[t] - s;
#pragma unroll
    for (int i = 0; i < 8; ++i) {
        int idx = base + t * 8 + i;
        if (idx < N_NODES) off[idx] = run;
        run += v[i];
    }
    if (t == 255) partial[blockIdx.x] = sdata[255];
}

__global__ void k_scan2(int* partial) {
    if (threadIdx.x == 0 && blockIdx.x == 0) {
        int run = 0;
        for (int i = 0; i < NBLK_SCAN; ++i) {
            int v = partial[i];
            partial[i] = run;
            run += v;
        }
    }
}

__global__ void k_scan3(int* __restrict__ off, const int* __restrict__ partial,
                        int* __restrict__ cur) {
    int i = blockIdx.x * 256 + threadIdx.x;
    if (i < N_NODES) {
        int o = off[i] + partial[i >> 11];
        off[i] = o;
        cur[i] = o;
    }
}

__global__ void k_fill(const int* __restrict__ ei, int* cur, int* __restrict__ csr_src) {
    int e = blockIdx.x * 256 + threadIdx.x;
    if (e < N_EDGES) {
        int s = ei[e];
        int d = ei[N_EDGES + e];
        int pos = atomicAdd(&cur[d], 1);
        csr_src[pos] = s;
    }
}

// ---------------- graph boundaries (batch is sorted) ----------------
__global__ void k_bounds(const int* __restrict__ batch, int* __restrict__ gstart) {
    int g = blockIdx.x * 256 + threadIdx.x;
    if (g > N_GRAPHS) return;
    int lo = 0, hi = N_NODES;
    while (lo < hi) {
        int mid = (lo + hi) >> 1;
        if (batch[mid] < g) lo = mid + 1;
        else hi = mid;
    }
    gstart[g] = lo;
}

// ---------------- bf16 conversions ----------------
__global__ void k_xconv(const float* __restrict__ x, unsigned short* __restrict__ xb) {
    int i = blockIdx.x * 256 + threadIdx.x;
    if (i >= N_NODES * K1PAD) return;
    int node = i / K1PAD;
    int k = i - node * K1PAD;
    xb[i] = (k < INDIM) ? f2bf(x[(size_t)node * INDIM + k]) : (unsigned short)0;
}

// W [KSRC][256] f32 -> Wb chunked [KPAD/32][256][32] bf16, zero-padded in k
__global__ void k_wconv(const float* __restrict__ W, unsigned short* __restrict__ Wb,
                        int KPAD, int KSRC) {
    int i = blockIdx.x * 256 + threadIdx.x;
    if (i >= 256 * KPAD) return;
    int kc = i >> 13;
    int r = i & 8191;
    int n = r >> 5;
    int kk = r & 31;
    int k = kc * 32 + kk;
    Wb[i] = (k < KSRC) ? f2bf(W[(size_t)k * HID + n]) : (unsigned short)0;
}

// ---------------- MFMA GEMM: C[N,256] = A_bf16[N,K] @ W_bf16[K,256] ----------------
// 256 threads = 4 waves; BM=64 (16 rows/wave); B direct from global (L1/L2-resident);
// A direct from global (each 64B chunk read exactly once). No LDS.
template <int K>
__global__ __launch_bounds__(256) void k_gemm_mfma(const unsigned short* __restrict__ A,
                                                   const unsigned short* __restrict__ Wb,
                                                   float* __restrict__ Cf,
                                                   unsigned short* __restrict__ Cb) {
    const int w = threadIdx.x >> 6;
    const int l = threadIdx.x & 63;
    const int lr = l & 15;   // A row-in-tile / B col-in-tile
    const int lg = l >> 4;   // k-group (8 bf16 each)

    int row = blockIdx.x * 64 + w * 16 + lr;
    int rc = row < N_NODES ? row : (N_NODES - 1);  // clamp; garbage only affects unstored rows
    const unsigned short* arow = A + (size_t)rc * K + lg * 8;

    f32x4 acc[16] = {};

    for (int kc = 0; kc < K / 32; ++kc) {
        bf16x8 a = *reinterpret_cast<const bf16x8*>(arow + kc * 32);
        const unsigned short* wb = Wb + (size_t)kc * (HID * 32) + lr * 32 + lg * 8;
#pragma unroll
        for (int nt = 0; nt < 16; ++nt) {
            bf16x8 b = *reinterpret_cast<const bf16x8*>(wb + nt * 512);
            acc[nt] = __builtin_amdgcn_mfma_f32_16x16x32_bf16(a, b, acc[nt], 0, 0, 0);
        }
    }

    // C/D layout: col = lane&15, row = (lane>>4)*4 + j
    int gr0 = blockIdx.x * 64 + w * 16 + lg * 4;
#pragma unroll
    for (int j = 0; j < 4; ++j) {
        int gr = gr0 + j;
        if (gr < N_NODES) {
            size_t base = (size_t)gr * HID + lr;
#pragma unroll
            for (int nt = 0; nt < 16; ++nt) {
                float v = acc[nt][j];
                Cf[base + nt * 16] = v;
                Cb[base + nt * 16] = f2bf(v);
            }
        }
    }
}

// ---------------- fused aggregate: hb = bf16(relu(b + dinv^2*tmp_self + sum norm*tmp[src])) ----------------
__global__ void k_aggregate(const float* __restrict__ tf, const unsigned short* __restrict__ tb,
                            const float* __restrict__ dinv, const int* __restrict__ off,
                            const int* __restrict__ cnt, const int* __restrict__ csr_src,
                            const float* __restrict__ bias, unsigned short* __restrict__ hb) {
    int node = blockIdx.x * 4 + (threadIdx.x >> 6);
    if (node >= N_NODES) return;
    int lane = threadIdx.x & 63;
    float di = dinv[node];
    float s2 = di * di;
    float4 v = *reinterpret_cast<const float4*>(&tf[(size_t)node * HID + lane * 4]);
    float4 bb = *reinterpret_cast<const float4*>(&bias[lane * 4]);
    float4 acc = {fmaf(v.x, s2, bb.x), fmaf(v.y, s2, bb.y),
                  fmaf(v.z, s2, bb.z), fmaf(v.w, s2, bb.w)};

    int o0 = off[node];
    int n = cnt[node];
    for (int j = 0; j < n; ++j) {
        int s = csr_src[o0 + j];
        float norm = dinv[s] * di;
        ushort4 u = *reinterpret_cast<const ushort4*>(&tb[(size_t)s * HID + lane * 4]);
        acc.x = fmaf(norm, bf2f(u.x), acc.x);
        acc.y = fmaf(norm, bf2f(u.y), acc.y);
        acc.z = fmaf(norm, bf2f(u.z), acc.z);
        acc.w = fmaf(norm, bf2f(u.w), acc.w);
    }
    ushort4 o;
    o.x = f2bf(fmaxf(acc.x, 0.0f));
    o.y = f2bf(fmaxf(acc.y, 0.0f));
    o.z = f2bf(fmaxf(acc.z, 0.0f));
    o.w = f2bf(fmaxf(acc.w, 0.0f));
    *reinterpret_cast<ushort4*>(&hb[(size_t)node * HID + lane * 4]) = o;
}

// ---------------- pool: one wave per graph, contiguous rows, register max ----------------
__global__ void k_pool2(const unsigned short* __restrict__ hb, const int* __restrict__ gstart,
                        float* __restrict__ out) {
    int g = blockIdx.x;
    int lane = threadIdx.x;
    int s = gstart[g], e = gstart[g + 1];
    float4 m = {0.0f, 0.0f, 0.0f, 0.0f};  // relu output >= 0
    for (int i = s; i < e; ++i) {
        ushort4 u = *reinterpret_cast<const ushort4*>(&hb[(size_t)i * HID + lane * 4]);
        m.x = fmaxf(m.x, bf2f(u.x));
        m.y = fmaxf(m.y, bf2f(u.y));
        m.z = fmaxf(m.z, bf2f(u.z));
        m.w = fmaxf(m.w, bf2f(u.w));
    }
    *reinterpret_cast<float4*>(&out[(size_t)g * HID + lane * 4]) = m;
}

extern "C" void kernel_launch(void* const* d_in, const int* in_sizes, int n_in,
                              void* d_out, int out_size, void* d_ws, size_t ws_size,
                              hipStream_t stream) {
    const float* x = (const float*)d_in[0];
    const int* ei = (const int*)d_in[1];
    const int* batch = (const int*)d_in[2];
    const float* W1 = (const float*)d_in[4];
    const float* b1 = (const float*)d_in[5];
    const float* W2 = (const float*)d_in[6];
    const float* b2 = (const float*)d_in[7];
    const float* W3 = (const float*)d_in[8];
    const float* b3 = (const float*)d_in[9];
    float* out = (float*)d_out;

    // workspace layout (total ~209.0 MB, <= round-2 proven usage)
    char* ws = (char*)d_ws;
    float* dinv = (float*)(ws);
    int* cnt = (int*)(ws + (512 << 10));
    int* off = (int*)(ws + (1024 << 10));
    int* cur = (int*)(ws + (1536 << 10));
    int* part = (int*)(ws + (2048 << 10));
    int* gstart = (int*)(ws + (2048 << 10) + 4096);
    int* csr_src = (int*)(ws + (2176 << 10));
    unsigned short* Wb1 = (unsigned short*)(ws + (3584 << 10));  // 48 KB
    unsigned short* Wb2 = (unsigned short*)(ws + (3712 << 10));  // 128 KB
    unsigned short* Wb3 = (unsigned short*)(ws + (3840 << 10));  // 128 KB
    float* tmp_f = (float*)(ws + (4096 << 10));                                  // 102.4 MB
    unsigned short* tmp_b = (unsigned short*)(ws + (4096 << 10) + 102400000);    // 51.2 MB
    unsigned short* h_b = (unsigned short*)(ws + (4096 << 10) + 153600000);      // 51.2 MB
    unsigned short* x_b = h_b;  // alias: x_b dead before h_b first written

    const int nblk_nodes = (N_NODES + 255) / 256;
    const int nblk_edges = (N_EDGES + 255) / 256;
    const int nblk_rows4 = (N_NODES + 3) / 4;
    const int nblk_gemm = (N_NODES + 63) / 64;

    // ---- CSR + dinv + graph bounds ----
    k_cnt_init<<<nblk_nodes, 256, 0, stream>>>(cnt);
    k_cnt_acc<<<nblk_edges, 256, 0, stream>>>(ei, cnt);
    k_dinv<<<nblk_nodes, 256, 0, stream>>>(cnt, dinv);
    k_scan1<<<NBLK_SCAN, 256, 0, stream>>>(cnt, off, part);
    k_scan2<<<1, 64, 0, stream>>>(part);
    k_scan3<<<nblk_nodes, 256, 0, stream>>>(off, part, cur);
    k_fill<<<nblk_edges, 256, 0, stream>>>(ei, cur, csr_src);
    k_bounds<<<(N_GRAPHS + 256) / 256, 256, 0, stream>>>(batch, gstart);

    // ---- bf16 conversions ----
    k_xconv<<<(N_NODES * K1PAD + 255) / 256, 256, 0, stream>>>(x, x_b);
    k_wconv<<<(256 * K1PAD + 255) / 256, 256, 0, stream>>>(W1, Wb1, K1PAD, INDIM);
    k_wconv<<<(256 * HID + 255) / 256, 256, 0, stream>>>(W2, Wb2, HID, HID);
    k_wconv<<<(256 * HID + 255) / 256, 256, 0, stream>>>(W3, Wb3, HID, HID);

    // ---- layer 1 ----
    k_gemm_mfma<K1PAD><<<nblk_gemm, 256, 0, stream>>>(x_b, Wb1, tmp_f, tmp_b);
    k_aggregate<<<nblk_rows4, 256, 0, stream>>>(tmp_f, tmp_b, dinv, off, cnt, csr_src, b1, h_b);

    // ---- layer 2 ----
    k_gemm_mfma<HID><<<nblk_gemm, 256, 0, stream>>>(h_b, Wb2, tmp_f, tmp_b);
    k_aggregate<<<nblk_rows4, 256, 0, stream>>>(tmp_f, tmp_b, dinv, off, cnt, csr_src, b2, h_b);

    // ---- layer 3 ----
    k_gemm_mfma<HID><<<nblk_gemm, 256, 0, stream>>>(h_b, Wb3, tmp_f, tmp_b);
    k_aggregate<<<nblk_rows4, 256, 0, stream>>>(tmp_f, tmp_b, dinv, off, cnt, csr_src, b3, h_b);

    // ---- pool ----
    k_pool2<<<N_GRAPHS, 64, 0, stream>>>(h_b, gstart, out);
}

// Round 5
// 465.114 us; speedup vs baseline: 8.3925x; 1.0980x over previous
//
#include <hip/hip_runtime.h>
#include <cstdint>
#include <cstddef>

#define N_NODES 100000
#define N_EDGES 300000
#define N_GRAPHS 2000
#define HID 256
#define INDIM 82
#define K1PAD 96
#define SCAN_CHUNK 2048
#define NBLK_SCAN ((N_NODES + SCAN_CHUNK - 1) / SCAN_CHUNK)  // 49

typedef __bf16 bf16x8 __attribute__((ext_vector_type(8)));
typedef float f32x4 __attribute__((ext_vector_type(4)));

__device__ __forceinline__ unsigned short f2bf(float f) {
    unsigned int u = __float_as_uint(f);
    u = (u + 0x7fffu + ((u >> 16) & 1u)) >> 16;  // RNE
    return (unsigned short)u;
}
__device__ __forceinline__ float bf2f(unsigned short s) {
    return __uint_as_float(((unsigned int)s) << 16);
}

// ---------------- degree counting / dinv ----------------
__global__ void k_cnt_init(int* cnt) {
    int i = blockIdx.x * 256 + threadIdx.x;
    if (i < N_NODES) cnt[i] = 0;
}

__global__ void k_cnt_acc(const int* __restrict__ ei, int* cnt) {
    int e = blockIdx.x * 256 + threadIdx.x;
    if (e < N_EDGES) atomicAdd(&cnt[ei[N_EDGES + e]], 1);
}

__global__ void k_dinv(const int* __restrict__ cnt, float* dinv) {
    int i = blockIdx.x * 256 + threadIdx.x;
    if (i < N_NODES) dinv[i] = rsqrtf((float)cnt[i] + 1.0f);
}

// ---------------- exclusive prefix sum ----------------
__global__ __launch_bounds__(256) void k_scan1(const int* __restrict__ cnt, int* __restrict__ off,
                                               int* __restrict__ partial) {
    __shared__ int sdata[256];
    const int base = blockIdx.x * SCAN_CHUNK;
    const int t = threadIdx.x;
    int v[8];
    int s = 0;
#pragma unroll
    for (int i = 0; i < 8; ++i) {
        int idx = base + t * 8 + i;
        v[i] = (idx < N_NODES) ? cnt[idx] : 0;
        s += v[i];
    }
    sdata[t] = s;
    __syncthreads();
    for (int d = 1; d < 256; d <<= 1) {
        int x = (t >= d) ? sdata[t - d] : 0;
        __syncthreads();
        sdata[t] += x;
        __syncthreads();
    }
    int run = sdata[t] - s;
#pragma unroll
    for (int i = 0; i < 8; ++i) {
        int idx = base + t * 8 + i;
        if (idx < N_NODES) off[idx] = run;
        run += v[i];
    }
    if (t == 255) partial[blockIdx.x] = sdata[255];
}

__global__ void k_scan2(int* partial) {
    if (threadIdx.x == 0 && blockIdx.x == 0) {
        int run = 0;
        for (int i = 0; i < NBLK_SCAN; ++i) {
            int v = partial[i];
            partial[i] = run;
            run += v;
        }
    }
}

__global__ void k_scan3(int* __restrict__ off, const int* __restrict__ partial,
                        int* __restrict__ cur) {
    int i = blockIdx.x * 256 + threadIdx.x;
    if (i < N_NODES) {
        int o = off[i] + partial[i >> 11];
        off[i] = o;
        cur[i] = o;
    }
}

__global__ void k_fill(const int* __restrict__ ei, int* cur, int* __restrict__ csr_src) {
    int e = blockIdx.x * 256 + threadIdx.x;
    if (e < N_EDGES) {
        int s = ei[e];
        int d = ei[N_EDGES + e];
        int pos = atomicAdd(&cur[d], 1);
        csr_src[pos] = s;
    }
}

// ---------------- graph boundaries (batch is sorted) ----------------
__global__ void k_bounds(const int* __restrict__ batch, int* __restrict__ gstart) {
    int g = blockIdx.x * 256 + threadIdx.x;
    if (g > N_GRAPHS) return;
    int lo = 0, hi = N_NODES;
    while (lo < hi) {
        int mid = (lo + hi) >> 1;
        if (batch[mid] < g) lo = mid + 1;
        else hi = mid;
    }
    gstart[g] = lo;
}

// ---------------- bf16 conversions ----------------
__global__ void k_xconv(const float* __restrict__ x, unsigned short* __restrict__ xb) {
    int i = blockIdx.x * 256 + threadIdx.x;
    if (i >= N_NODES * K1PAD) return;
    int node = i / K1PAD;
    int k = i - node * K1PAD;
    xb[i] = (k < INDIM) ? f2bf(x[(size_t)node * INDIM + k]) : (unsigned short)0;
}

// W [KSRC][256] f32 -> Wb chunked [KPAD/32][256][32] bf16, zero-padded in k
__global__ void k_wconv(const float* __restrict__ W, unsigned short* __restrict__ Wb,
                        int KPAD, int KSRC) {
    int i = blockIdx.x * 256 + threadIdx.x;
    if (i >= 256 * KPAD) return;
    int kc = i >> 13;
    int r = i & 8191;
    int n = r >> 5;
    int kk = r & 31;
    int k = kc * 32 + kk;
    Wb[i] = (k < KSRC) ? f2bf(W[(size_t)k * HID + n]) : (unsigned short)0;
}

// ---------------- MFMA GEMM: Cb[N,256] = A_bf16[N,K] @ W_bf16[K,256] ----------------
// 256 threads = 4 waves; 32 rows per wave (2 A fragments per MFMA step);
// B direct from global (L1/L2-resident); bf16 output only.
template <int K>
__global__ __launch_bounds__(256) void k_gemm_mfma(const unsigned short* __restrict__ A,
                                                   const unsigned short* __restrict__ Wb,
                                                   unsigned short* __restrict__ Cb) {
    const int w = threadIdx.x >> 6;
    const int l = threadIdx.x & 63;
    const int lr = l & 15;   // A row-in-frag / B col-in-frag
    const int lg = l >> 4;   // k-group (8 bf16 each)

    const int rowbase = blockIdx.x * 128 + w * 32;
    int r0 = rowbase + lr;
    int r1 = rowbase + 16 + lr;
    int r0c = r0 < N_NODES ? r0 : (N_NODES - 1);
    int r1c = r1 < N_NODES ? r1 : (N_NODES - 1);
    const unsigned short* a0p = A + (size_t)r0c * K + lg * 8;
    const unsigned short* a1p = A + (size_t)r1c * K + lg * 8;

    f32x4 acc0[16] = {};
    f32x4 acc1[16] = {};

#pragma unroll
    for (int kc = 0; kc < K / 32; ++kc) {
        bf16x8 a0 = *reinterpret_cast<const bf16x8*>(a0p + kc * 32);
        bf16x8 a1 = *reinterpret_cast<const bf16x8*>(a1p + kc * 32);
        const unsigned short* wb = Wb + (size_t)kc * (HID * 32) + lr * 32 + lg * 8;
#pragma unroll
        for (int nt = 0; nt < 16; ++nt) {
            bf16x8 b = *reinterpret_cast<const bf16x8*>(wb + nt * 512);
            acc0[nt] = __builtin_amdgcn_mfma_f32_16x16x32_bf16(a0, b, acc0[nt], 0, 0, 0);
            acc1[nt] = __builtin_amdgcn_mfma_f32_16x16x32_bf16(a1, b, acc1[nt], 0, 0, 0);
        }
    }

    // C/D layout: col = lane&15, row = (lane>>4)*4 + j
    int gr0 = rowbase + lg * 4;
#pragma unroll
    for (int j = 0; j < 4; ++j) {
        int gr = gr0 + j;
        if (gr < N_NODES) {
            size_t base = (size_t)gr * HID + lr;
#pragma unroll
            for (int nt = 0; nt < 16; ++nt) Cb[base + nt * 16] = f2bf(acc0[nt][j]);
        }
        int gr2 = gr + 16;
        if (gr2 < N_NODES) {
            size_t base = (size_t)gr2 * HID + lr;
#pragma unroll
            for (int nt = 0; nt < 16; ++nt) Cb[base + nt * 16] = f2bf(acc1[nt][j]);
        }
    }
}

// ---------------- fused aggregate: hb = bf16(relu(b + dinv^2*tb_self + sum norm*tb[src])) ----------------
__global__ void k_aggregate(const unsigned short* __restrict__ tb,
                            const float* __restrict__ dinv, const int* __restrict__ off,
                            const int* __restrict__ cnt, const int* __restrict__ csr_src,
                            const float* __restrict__ bias, unsigned short* __restrict__ hb) {
    int node = blockIdx.x * 4 + (threadIdx.x >> 6);
    if (node >= N_NODES) return;
    int lane = threadIdx.x & 63;
    float di = dinv[node];
    float s2 = di * di;
    ushort4 sv = *reinterpret_cast<const ushort4*>(&tb[(size_t)node * HID + lane * 4]);
    float4 bb = *reinterpret_cast<const float4*>(&bias[lane * 4]);
    float4 acc = {fmaf(bf2f(sv.x), s2, bb.x), fmaf(bf2f(sv.y), s2, bb.y),
                  fmaf(bf2f(sv.z), s2, bb.z), fmaf(bf2f(sv.w), s2, bb.w)};

    int o0 = off[node];
    int n = cnt[node];
    for (int j = 0; j < n; ++j) {
        int s = csr_src[o0 + j];
        float norm = dinv[s] * di;
        ushort4 u = *reinterpret_cast<const ushort4*>(&tb[(size_t)s * HID + lane * 4]);
        acc.x = fmaf(norm, bf2f(u.x), acc.x);
        acc.y = fmaf(norm, bf2f(u.y), acc.y);
        acc.z = fmaf(norm, bf2f(u.z), acc.z);
        acc.w = fmaf(norm, bf2f(u.w), acc.w);
    }
    ushort4 o;
    o.x = f2bf(fmaxf(acc.x, 0.0f));
    o.y = f2bf(fmaxf(acc.y, 0.0f));
    o.z = f2bf(fmaxf(acc.z, 0.0f));
    o.w = f2bf(fmaxf(acc.w, 0.0f));
    *reinterpret_cast<ushort4*>(&hb[(size_t)node * HID + lane * 4]) = o;
}

// ---------------- pool: one wave per graph, contiguous rows, register max ----------------
__global__ void k_pool2(const unsigned short* __restrict__ hb, const int* __restrict__ gstart,
                        float* __restrict__ out) {
    int g = blockIdx.x;
    int lane = threadIdx.x;
    int s = gstart[g], e = gstart[g + 1];
    float4 m = {0.0f, 0.0f, 0.0f, 0.0f};  // relu output >= 0
    for (int i = s; i < e; ++i) {
        ushort4 u = *reinterpret_cast<const ushort4*>(&hb[(size_t)i * HID + lane * 4]);
        m.x = fmaxf(m.x, bf2f(u.x));
        m.y = fmaxf(m.y, bf2f(u.y));
        m.z = fmaxf(m.z, bf2f(u.z));
        m.w = fmaxf(m.w, bf2f(u.w));
    }
    *reinterpret_cast<float4*>(&out[(size_t)g * HID + lane * 4]) = m;
}

extern "C" void kernel_launch(void* const* d_in, const int* in_sizes, int n_in,
                              void* d_out, int out_size, void* d_ws, size_t ws_size,
                              hipStream_t stream) {
    const float* x = (const float*)d_in[0];
    const int* ei = (const int*)d_in[1];
    const int* batch = (const int*)d_in[2];
    const float* W1 = (const float*)d_in[4];
    const float* b1 = (const float*)d_in[5];
    const float* W2 = (const float*)d_in[6];
    const float* b2 = (const float*)d_in[7];
    const float* W3 = (const float*)d_in[8];
    const float* b3 = (const float*)d_in[9];
    float* out = (float*)d_out;

    // workspace layout (~107 MB total)
    char* ws = (char*)d_ws;
    float* dinv = (float*)(ws);
    int* cnt = (int*)(ws + (512 << 10));
    int* off = (int*)(ws + (1024 << 10));
    int* cur = (int*)(ws + (1536 << 10));
    int* part = (int*)(ws + (2048 << 10));
    int* gstart = (int*)(ws + (2048 << 10) + 4096);
    int* csr_src = (int*)(ws + (2176 << 10));
    unsigned short* Wb1 = (unsigned short*)(ws + (3584 << 10));  // 48 KB
    unsigned short* Wb2 = (unsigned short*)(ws + (3712 << 10));  // 128 KB
    unsigned short* Wb3 = (unsigned short*)(ws + (3840 << 10));  // 128 KB
    unsigned short* tmp_b = (unsigned short*)(ws + (4096 << 10));                // 51.2 MB
    unsigned short* h_b = (unsigned short*)(ws + (4096 << 10) + 51200000);       // 51.2 MB
    unsigned short* x_b = h_b;  // alias: x_b dead before h_b first written

    const int nblk_nodes = (N_NODES + 255) / 256;
    const int nblk_edges = (N_EDGES + 255) / 256;
    const int nblk_rows4 = (N_NODES + 3) / 4;
    const int nblk_gemm = (N_NODES + 127) / 128;

    // ---- CSR + dinv + graph bounds ----
    k_cnt_init<<<nblk_nodes, 256, 0, stream>>>(cnt);
    k_cnt_acc<<<nblk_edges, 256, 0, stream>>>(ei, cnt);
    k_dinv<<<nblk_nodes, 256, 0, stream>>>(cnt, dinv);
    k_scan1<<<NBLK_SCAN, 256, 0, stream>>>(cnt, off, part);
    k_scan2<<<1, 64, 0, stream>>>(part);
    k_scan3<<<nblk_nodes, 256, 0, stream>>>(off, part, cur);
    k_fill<<<nblk_edges, 256, 0, stream>>>(ei, cur, csr_src);
    k_bounds<<<(N_GRAPHS + 256) / 256, 256, 0, stream>>>(batch, gstart);

    // ---- bf16 conversions ----
    k_xconv<<<(N_NODES * K1PAD + 255) / 256, 256, 0, stream>>>(x, x_b);
    k_wconv<<<(256 * K1PAD + 255) / 256, 256, 0, stream>>>(W1, Wb1, K1PAD, INDIM);
    k_wconv<<<(256 * HID + 255) / 256, 256, 0, stream>>>(W2, Wb2, HID, HID);
    k_wconv<<<(256 * HID + 255) / 256, 256, 0, stream>>>(W3, Wb3, HID, HID);

    // ---- layer 1 ----
    k_gemm_mfma<K1PAD><<<nblk_gemm, 256, 0, stream>>>(x_b, Wb1, tmp_b);
    k_aggregate<<<nblk_rows4, 256, 0, stream>>>(tmp_b, dinv, off, cnt, csr_src, b1, h_b);

    // ---- layer 2 ----
    k_gemm_mfma<HID><<<nblk_gemm, 256, 0, stream>>>(h_b, Wb2, tmp_b);
    k_aggregate<<<nblk_rows4, 256, 0, stream>>>(tmp_b, dinv, off, cnt, csr_src, b2, h_b);

    // ---- layer 3 ----
    k_gemm_mfma<HID><<<nblk_gemm, 256, 0, stream>>>(h_b, Wb3, tmp_b);
    k_aggregate<<<nblk_rows4, 256, 0, stream>>>(tmp_b, dinv, off, cnt, csr_src, b3, h_b);

    // ---- pool ----
    k_pool2<<<N_GRAPHS, 64, 0, stream>>>(h_b, gstart, out);
}

// Round 6
// 306.987 us; speedup vs baseline: 12.7154x; 1.5151x over previous
//
#include <hip/hip_runtime.h>
#include <cstdint>
#include <cstddef>

#define N_NODES 100000
#define N_EDGES 300000
#define N_GRAPHS 2000
#define HID 256
#define INDIM 82
#define K1PAD 96
#define SCAN_CHUNK 2048
#define NBLK_SCAN ((N_NODES + SCAN_CHUNK - 1) / SCAN_CHUNK)  // 49

typedef __bf16 bf16x8 __attribute__((ext_vector_type(8)));
typedef float f32x4 __attribute__((ext_vector_type(4)));

__device__ __forceinline__ unsigned short f2bf(float f) {
    unsigned int u = __float_as_uint(f);
    u = (u + 0x7fffu + ((u >> 16) & 1u)) >> 16;  // RNE
    return (unsigned short)u;
}
__device__ __forceinline__ float bf2f(unsigned short s) {
    return __uint_as_float(((unsigned int)s) << 16);
}

// ---------------- degree counting / dinv ----------------
__global__ void k_cnt_init(int* cnt) {
    int i = blockIdx.x * 256 + threadIdx.x;
    if (i < N_NODES) cnt[i] = 0;
}

__global__ void k_cnt_acc(const int* __restrict__ ei, int* cnt) {
    int e = blockIdx.x * 256 + threadIdx.x;
    if (e < N_EDGES) atomicAdd(&cnt[ei[N_EDGES + e]], 1);
}

__global__ void k_dinv(const int* __restrict__ cnt, float* dinv) {
    int i = blockIdx.x * 256 + threadIdx.x;
    if (i < N_NODES) dinv[i] = rsqrtf((float)cnt[i] + 1.0f);
}

// ---------------- exclusive prefix sum ----------------
__global__ __launch_bounds__(256) void k_scan1(const int* __restrict__ cnt, int* __restrict__ off,
                                               int* __restrict__ partial) {
    __shared__ int sdata[256];
    const int base = blockIdx.x * SCAN_CHUNK;
    const int t = threadIdx.x;
    int v[8];
    int s = 0;
#pragma unroll
    for (int i = 0; i < 8; ++i) {
        int idx = base + t * 8 + i;
        v[i] = (idx < N_NODES) ? cnt[idx] : 0;
        s += v[i];
    }
    sdata[t] = s;
    __syncthreads();
    for (int d = 1; d < 256; d <<= 1) {
        int x = (t >= d) ? sdata[t - d] : 0;
        __syncthreads();
        sdata[t] += x;
        __syncthreads();
    }
    int run = sdata[t] - s;
#pragma unroll
    for (int i = 0; i < 8; ++i) {
        int idx = base + t * 8 + i;
        if (idx < N_NODES) off[idx] = run;
        run += v[i];
    }
    if (t == 255) partial[blockIdx.x] = sdata[255];
}

__global__ void k_scan2(int* partial) {
    if (threadIdx.x == 0 && blockIdx.x == 0) {
        int run = 0;
        for (int i = 0; i < NBLK_SCAN; ++i) {
            int v = partial[i];
            partial[i] = run;
            run += v;
        }
    }
}

__global__ void k_scan3(int* __restrict__ off, const int* __restrict__ partial,
                        int* __restrict__ cur) {
    int i = blockIdx.x * 256 + threadIdx.x;
    if (i < N_NODES) {
        int o = off[i] + partial[i >> 11];
        off[i] = o;
        cur[i] = o;
    }
}

__global__ void k_fill(const int* __restrict__ ei, int* cur, int* __restrict__ csr_src) {
    int e = blockIdx.x * 256 + threadIdx.x;
    if (e < N_EDGES) {
        int s = ei[e];
        int d = ei[N_EDGES + e];
        int pos = atomicAdd(&cur[d], 1);
        csr_src[pos] = s;
    }
}

// ---------------- graph boundaries (batch is sorted) ----------------
__global__ void k_bounds(const int* __restrict__ batch, int* __restrict__ gstart) {
    int g = blockIdx.x * 256 + threadIdx.x;
    if (g > N_GRAPHS) return;
    int lo = 0, hi = N_NODES;
    while (lo < hi) {
        int mid = (lo + hi) >> 1;
        if (batch[mid] < g) lo = mid + 1;
        else hi = mid;
    }
    gstart[g] = lo;
}

// ---------------- bf16 conversions ----------------
__global__ void k_xconv(const float* __restrict__ x, unsigned short* __restrict__ xb) {
    int i = blockIdx.x * 256 + threadIdx.x;
    if (i >= N_NODES * K1PAD) return;
    int node = i / K1PAD;
    int k = i - node * K1PAD;
    xb[i] = (k < INDIM) ? f2bf(x[(size_t)node * INDIM + k]) : (unsigned short)0;
}

// W [KSRC][256] f32 -> Wb fragment-contiguous: [kc][nt][lg][lr][j]
// offset = kc*8192 + nt*512 + lg*128 + lr*8 + j ; holds W[kc*32+lg*8+j][nt*16+lr]
__global__ void k_wconv(const float* __restrict__ W, unsigned short* __restrict__ Wb,
                        int KPAD, int KSRC) {
    int i = blockIdx.x * 256 + threadIdx.x;
    if (i >= 256 * KPAD) return;
    int kc = i >> 13;
    int r = i & 8191;
    int nt = r >> 9;
    int r2 = r & 511;
    int lg = r2 >> 7;
    int lr = (r2 >> 3) & 15;
    int j = r2 & 7;
    int k = kc * 32 + lg * 8 + j;
    int n = nt * 16 + lr;
    Wb[i] = (k < KSRC) ? f2bf(W[(size_t)k * HID + n]) : (unsigned short)0;
}

// ---------------- MFMA GEMM: Cb[N,256] = A_bf16[N,K] @ W_bf16[K,256] ----------------
// 512 threads = 8 waves x 32 rows = 256 rows/block. A fully in registers (loaded
// upfront); W staged global->reg->LDS, double-buffered per 32-k chunk (16 KB).
// B-fragment reads are 1 KB contiguous LDS per wave (conflict-free ds_read_b128).
template <int K>
__global__ __launch_bounds__(512) void k_gemm_mfma(const unsigned short* __restrict__ A,
                                                   const unsigned short* __restrict__ Wb,
                                                   unsigned short* __restrict__ Cb) {
    constexpr int NK = K / 32;
    __shared__ __align__(16) unsigned short buf[2][8192];  // 2 x 16 KB

    const int tid = threadIdx.x;
    const int w = tid >> 6;
    const int l = tid & 63;
    const int lr = l & 15;
    const int lg = l >> 4;

    const int rowbase = blockIdx.x * 256 + w * 32;
    int r0 = rowbase + lr;
    int r1 = rowbase + 16 + lr;
    int r0c = r0 < N_NODES ? r0 : (N_NODES - 1);
    int r1c = r1 < N_NODES ? r1 : (N_NODES - 1);
    const unsigned short* a0p = A + (size_t)r0c * K + lg * 8;
    const unsigned short* a1p = A + (size_t)r1c * K + lg * 8;

    // all of A upfront (independent loads, latency overlapped)
    bf16x8 a0[NK], a1[NK];
#pragma unroll
    for (int kc = 0; kc < NK; ++kc) {
        a0[kc] = *reinterpret_cast<const bf16x8*>(a0p + kc * 32);
        a1[kc] = *reinterpret_cast<const bf16x8*>(a1p + kc * 32);
    }

    // stage chunk 0 into regs
    uint4 st0 = *reinterpret_cast<const uint4*>(Wb + tid * 8);
    uint4 st1 = *reinterpret_cast<const uint4*>(Wb + 4096 + tid * 8);

    f32x4 acc0[16] = {};
    f32x4 acc1[16] = {};

#pragma unroll
    for (int kc = 0; kc < NK; ++kc) {
        // commit staged chunk kc to LDS (contiguous 16B/thread: conflict-free)
        unsigned short* b = buf[kc & 1];
        *reinterpret_cast<uint4*>(b + tid * 8) = st0;
        *reinterpret_cast<uint4*>(b + 4096 + tid * 8) = st1;
        // issue next chunk's global loads; results consumed next iteration,
        // so HBM/L2 latency hides under this iteration's MFMAs
        if (kc + 1 < NK) {
            const unsigned short* src = Wb + (size_t)(kc + 1) * 8192;
            st0 = *reinterpret_cast<const uint4*>(src + tid * 8);
            st1 = *reinterpret_cast<const uint4*>(src + 4096 + tid * 8);
        }
        __syncthreads();
        const unsigned short* bfp = buf[kc & 1] + (size_t)l * 8;
#pragma unroll
        for (int nt = 0; nt < 16; ++nt) {
            bf16x8 bb = *reinterpret_cast<const bf16x8*>(bfp + nt * 512);
            acc0[nt] = __builtin_amdgcn_mfma_f32_16x16x32_bf16(a0[kc], bb, acc0[nt], 0, 0, 0);
            acc1[nt] = __builtin_amdgcn_mfma_f32_16x16x32_bf16(a1[kc], bb, acc1[nt], 0, 0, 0);
        }
        __syncthreads();
    }

    // C/D layout: col = lane&15, row = (lane>>4)*4 + j
    int gr0 = rowbase + lg * 4;
#pragma unroll
    for (int j = 0; j < 4; ++j) {
        int gr = gr0 + j;
        if (gr < N_NODES) {
            size_t base = (size_t)gr * HID + lr;
#pragma unroll
            for (int nt = 0; nt < 16; ++nt) Cb[base + nt * 16] = f2bf(acc0[nt][j]);
        }
        int gr2 = gr + 16;
        if (gr2 < N_NODES) {
            size_t base = (size_t)gr2 * HID + lr;
#pragma unroll
            for (int nt = 0; nt < 16; ++nt) Cb[base + nt * 16] = f2bf(acc1[nt][j]);
        }
    }
}

// ---------------- fused aggregate: hb = bf16(relu(b + dinv^2*tb_self + sum norm*tb[src])) ----------------
__global__ void k_aggregate(const unsigned short* __restrict__ tb,
                            const float* __restrict__ dinv, const int* __restrict__ off,
                            const int* __restrict__ cnt, const int* __restrict__ csr_src,
                            const float* __restrict__ bias, unsigned short* __restrict__ hb) {
    int node = blockIdx.x * 4 + (threadIdx.x >> 6);
    if (node >= N_NODES) return;
    int lane = threadIdx.x & 63;
    float di = dinv[node];
    float s2 = di * di;
    ushort4 sv = *reinterpret_cast<const ushort4*>(&tb[(size_t)node * HID + lane * 4]);
    float4 bb = *reinterpret_cast<const float4*>(&bias[lane * 4]);
    float4 acc = {fmaf(bf2f(sv.x), s2, bb.x), fmaf(bf2f(sv.y), s2, bb.y),
                  fmaf(bf2f(sv.z), s2, bb.z), fmaf(bf2f(sv.w), s2, bb.w)};

    int o0 = off[node];
    int n = cnt[node];
    int j = 0;
    for (; j + 1 < n; j += 2) {  // 2-way unroll: independent gathers in flight
        int s0 = csr_src[o0 + j];
        int s1 = csr_src[o0 + j + 1];
        float n0 = dinv[s0] * di;
        float n1 = dinv[s1] * di;
        ushort4 u0 = *reinterpret_cast<const ushort4*>(&tb[(size_t)s0 * HID + lane * 4]);
        ushort4 u1 = *reinterpret_cast<const ushort4*>(&tb[(size_t)s1 * HID + lane * 4]);
        acc.x = fmaf(n0, bf2f(u0.x), acc.x);
        acc.y = fmaf(n0, bf2f(u0.y), acc.y);
        acc.z = fmaf(n0, bf2f(u0.z), acc.z);
        acc.w = fmaf(n0, bf2f(u0.w), acc.w);
        acc.x = fmaf(n1, bf2f(u1.x), acc.x);
        acc.y = fmaf(n1, bf2f(u1.y), acc.y);
        acc.z = fmaf(n1, bf2f(u1.z), acc.z);
        acc.w = fmaf(n1, bf2f(u1.w), acc.w);
    }
    if (j < n) {
        int s0 = csr_src[o0 + j];
        float n0 = dinv[s0] * di;
        ushort4 u0 = *reinterpret_cast<const ushort4*>(&tb[(size_t)s0 * HID + lane * 4]);
        acc.x = fmaf(n0, bf2f(u0.x), acc.x);
        acc.y = fmaf(n0, bf2f(u0.y), acc.y);
        acc.z = fmaf(n0, bf2f(u0.z), acc.z);
        acc.w = fmaf(n0, bf2f(u0.w), acc.w);
    }
    ushort4 o;
    o.x = f2bf(fmaxf(acc.x, 0.0f));
    o.y = f2bf(fmaxf(acc.y, 0.0f));
    o.z = f2bf(fmaxf(acc.z, 0.0f));
    o.w = f2bf(fmaxf(acc.w, 0.0f));
    *reinterpret_cast<ushort4*>(&hb[(size_t)node * HID + lane * 4]) = o;
}

// ---------------- pool: one wave per graph, contiguous rows, register max ----------------
__global__ void k_pool2(const unsigned short* __restrict__ hb, const int* __restrict__ gstart,
                        float* __restrict__ out) {
    int g = blockIdx.x;
    int lane = threadIdx.x;
    int s = gstart[g], e = gstart[g + 1];
    float4 m = {0.0f, 0.0f, 0.0f, 0.0f};  // relu output >= 0
    for (int i = s; i < e; ++i) {
        ushort4 u = *reinterpret_cast<const ushort4*>(&hb[(size_t)i * HID + lane * 4]);
        m.x = fmaxf(m.x, bf2f(u.x));
        m.y = fmaxf(m.y, bf2f(u.y));
        m.z = fmaxf(m.z, bf2f(u.z));
        m.w = fmaxf(m.w, bf2f(u.w));
    }
    *reinterpret_cast<float4*>(&out[(size_t)g * HID + lane * 4]) = m;
}

extern "C" void kernel_launch(void* const* d_in, const int* in_sizes, int n_in,
                              void* d_out, int out_size, void* d_ws, size_t ws_size,
                              hipStream_t stream) {
    const float* x = (const float*)d_in[0];
    const int* ei = (const int*)d_in[1];
    const int* batch = (const int*)d_in[2];
    const float* W1 = (const float*)d_in[4];
    const float* b1 = (const float*)d_in[5];
    const float* W2 = (const float*)d_in[6];
    const float* b2 = (const float*)d_in[7];
    const float* W3 = (const float*)d_in[8];
    const float* b3 = (const float*)d_in[9];
    float* out = (float*)d_out;

    // workspace layout (~107 MB total)
    char* ws = (char*)d_ws;
    float* dinv = (float*)(ws);
    int* cnt = (int*)(ws + (512 << 10));
    int* off = (int*)(ws + (1024 << 10));
    int* cur = (int*)(ws + (1536 << 10));
    int* part = (int*)(ws + (2048 << 10));
    int* gstart = (int*)(ws + (2048 << 10) + 4096);
    int* csr_src = (int*)(ws + (2176 << 10));
    unsigned short* Wb1 = (unsigned short*)(ws + (3584 << 10));  // 48 KB
    unsigned short* Wb2 = (unsigned short*)(ws + (3712 << 10));  // 128 KB
    unsigned short* Wb3 = (unsigned short*)(ws + (3840 << 10));  // 128 KB
    unsigned short* tmp_b = (unsigned short*)(ws + (4096 << 10));                // 51.2 MB
    unsigned short* h_b = (unsigned short*)(ws + (4096 << 10) + 51200000);       // 51.2 MB
    unsigned short* x_b = h_b;  // alias: x_b dead before h_b first written

    const int nblk_nodes = (N_NODES + 255) / 256;
    const int nblk_edges = (N_EDGES + 255) / 256;
    const int nblk_rows4 = (N_NODES + 3) / 4;
    const int nblk_gemm = (N_NODES + 255) / 256;  // 256 rows per block now

    // ---- CSR + dinv + graph bounds ----
    k_cnt_init<<<nblk_nodes, 256, 0, stream>>>(cnt);
    k_cnt_acc<<<nblk_edges, 256, 0, stream>>>(ei, cnt);
    k_dinv<<<nblk_nodes, 256, 0, stream>>>(cnt, dinv);
    k_scan1<<<NBLK_SCAN, 256, 0, stream>>>(cnt, off, part);
    k_scan2<<<1, 64, 0, stream>>>(part);
    k_scan3<<<nblk_nodes, 256, 0, stream>>>(off, part, cur);
    k_fill<<<nblk_edges, 256, 0, stream>>>(ei, cur, csr_src);
    k_bounds<<<(N_GRAPHS + 256) / 256, 256, 0, stream>>>(batch, gstart);

    // ---- bf16 conversions ----
    k_xconv<<<(N_NODES * K1PAD + 255) / 256, 256, 0, stream>>>(x, x_b);
    k_wconv<<<(256 * K1PAD + 255) / 256, 256, 0, stream>>>(W1, Wb1, K1PAD, INDIM);
    k_wconv<<<(256 * HID + 255) / 256, 256, 0, stream>>>(W2, Wb2, HID, HID);
    k_wconv<<<(256 * HID + 255) / 256, 256, 0, stream>>>(W3, Wb3, HID, HID);

    // ---- layer 1 ----
    k_gemm_mfma<K1PAD><<<nblk_gemm, 512, 0, stream>>>(x_b, Wb1, tmp_b);
    k_aggregate<<<nblk_rows4, 256, 0, stream>>>(tmp_b, dinv, off, cnt, csr_src, b1, h_b);

    // ---- layer 2 ----
    k_gemm_mfma<HID><<<nblk_gemm, 512, 0, stream>>>(h_b, Wb2, tmp_b);
    k_aggregate<<<nblk_rows4, 256, 0, stream>>>(tmp_b, dinv, off, cnt, csr_src, b2, h_b);

    // ---- layer 3 ----
    k_gemm_mfma<HID><<<nblk_gemm, 512, 0, stream>>>(h_b, Wb3, tmp_b);
    k_aggregate<<<nblk_rows4, 256, 0, stream>>>(tmp_b, dinv, off, cnt, csr_src, b3, h_b);

    // ---- pool ----
    k_pool2<<<N_GRAPHS, 64, 0, stream>>>(h_b, gstart, out);
}

// Round 7
// 282.721 us; speedup vs baseline: 13.8068x; 1.0858x over previous
//
#include <hip/hip_runtime.h>
#include <cstdint>
#include <cstddef>

#define N_NODES 100000
#define N_EDGES 300000
#define N_GRAPHS 2000
#define HID 256
#define INDIM 82
#define K1PAD 128
#define N_TILES ((N_NODES + 255) / 256)  // 391
#define SCAN_CHUNK 2048
#define NBLK_SCAN ((N_NODES + SCAN_CHUNK - 1) / SCAN_CHUNK)  // 49

typedef __bf16 bf16x8 __attribute__((ext_vector_type(8)));
typedef float f32x4 __attribute__((ext_vector_type(4)));

__device__ __forceinline__ unsigned short f2bf(float f) {
    unsigned int u = __float_as_uint(f);
    u = (u + 0x7fffu + ((u >> 16) & 1u)) >> 16;  // RNE
    return (unsigned short)u;
}
__device__ __forceinline__ float bf2f(unsigned short s) {
    return __uint_as_float(((unsigned int)s) << 16);
}

// ---------------- degree counting ----------------
__global__ void k_cnt_init(int* cnt) {
    int i = blockIdx.x * 256 + threadIdx.x;
    if (i < N_NODES) cnt[i] = 0;
}

__global__ void k_cnt_acc(const int* __restrict__ ei, int* cnt) {
    int e = blockIdx.x * 256 + threadIdx.x;
    if (e < N_EDGES) atomicAdd(&cnt[ei[N_EDGES + e]], 1);
}

// ---------------- exclusive prefix sum ----------------
__global__ __launch_bounds__(256) void k_scan1(const int* __restrict__ cnt, int* __restrict__ off,
                                               int* __restrict__ partial) {
    __shared__ int sdata[256];
    const int base = blockIdx.x * SCAN_CHUNK;
    const int t = threadIdx.x;
    int v[8];
    int s = 0;
#pragma unroll
    for (int i = 0; i < 8; ++i) {
        int idx = base + t * 8 + i;
        v[i] = (idx < N_NODES) ? cnt[idx] : 0;
        s += v[i];
    }
    sdata[t] = s;
    __syncthreads();
    for (int d = 1; d < 256; d <<= 1) {
        int x = (t >= d) ? sdata[t - d] : 0;
        __syncthreads();
        sdata[t] += x;
        __syncthreads();
    }
    int run = sdata[t] - s;
#pragma unroll
    for (int i = 0; i < 8; ++i) {
        int idx = base + t * 8 + i;
        if (idx < N_NODES) off[idx] = run;
        run += v[i];
    }
    if (t == 255) partial[blockIdx.x] = sdata[255];
}

__global__ void k_scan2(int* partial) {
    if (threadIdx.x == 0 && blockIdx.x == 0) {
        int run = 0;
        for (int i = 0; i < NBLK_SCAN; ++i) {
            int v = partial[i];
            partial[i] = run;
            run += v;
        }
    }
}

// scan fixup + cur init + dinv (merged)
__global__ void k_scan3(int* __restrict__ off, const int* __restrict__ partial,
                        int* __restrict__ cur, const int* __restrict__ cnt,
                        float* __restrict__ dinv) {
    int i = blockIdx.x * 256 + threadIdx.x;
    if (i < N_NODES) {
        int o = off[i] + partial[i >> 11];
        off[i] = o;
        cur[i] = o;
        dinv[i] = rsqrtf((float)cnt[i] + 1.0f);
    }
}

__global__ void k_fill(const int* __restrict__ ei, int* cur, int* __restrict__ csr_src) {
    int e = blockIdx.x * 256 + threadIdx.x;
    if (e < N_EDGES) {
        int s = ei[e];
        int d = ei[N_EDGES + e];
        int pos = atomicAdd(&cur[d], 1);
        csr_src[pos] = s;
    }
}

// ---------------- graph boundaries (batch is sorted) ----------------
__global__ void k_bounds(const int* __restrict__ batch, int* __restrict__ gstart) {
    int g = blockIdx.x * 256 + threadIdx.x;
    if (g > N_GRAPHS) return;
    int lo = 0, hi = N_NODES;
    while (lo < hi) {
        int mid = (lo + hi) >> 1;
        if (batch[mid] < g) lo = mid + 1;
        else hi = mid;
    }
    gstart[g] = lo;
}

// ---------------- bf16 conversions ----------------
__global__ void k_xconv(const float* __restrict__ x, unsigned short* __restrict__ xb) {
    int i = blockIdx.x * 256 + threadIdx.x;
    if (i >= N_NODES * K1PAD) return;
    int node = i >> 7;
    int k = i & 127;
    xb[i] = (k < INDIM) ? f2bf(x[(size_t)node * INDIM + k]) : (unsigned short)0;
}

// W [KSRC][256] f32 -> Wb fragment-contiguous: [kc][nt][lg][lr][j]
// offset = kc*8192 + nt*512 + lg*128 + lr*8 + j ; holds W[kc*32+lg*8+j][nt*16+lr]
__global__ void k_wconv(const float* __restrict__ W, unsigned short* __restrict__ Wb,
                        int KPAD, int KSRC) {
    int i = blockIdx.x * 256 + threadIdx.x;
    if (i >= 256 * KPAD) return;
    int kc = i >> 13;
    int r = i & 8191;
    int nt = r >> 9;
    int r2 = r & 511;
    int lg = r2 >> 7;
    int lr = (r2 >> 3) & 15;
    int j = r2 & 7;
    int k = kc * 32 + lg * 8 + j;
    int n = nt * 16 + lr;
    Wb[i] = (k < KSRC) ? f2bf(W[(size_t)k * HID + n]) : (unsigned short)0;
}

// ---------------- MFMA GEMM: Cb[N,256] = relu(A_bf16[N,K] @ W_bf16[K,256] + bias) ----------------
// 512 threads = 8 waves x 32 rows = 256 rows/tile. Whole W in LDS (loaded once,
// one barrier); persistent grid of 256 blocks loops over tiles; barrier-free K-loop.
template <int K>
__global__ __launch_bounds__(512) void k_gemm_mfma(const unsigned short* __restrict__ A,
                                                   const unsigned short* __restrict__ Wb,
                                                   const float* __restrict__ bias,
                                                   unsigned short* __restrict__ Cb) {
    constexpr int NK = K / 32;
    __shared__ __align__(16) unsigned short Wsh[K * HID];  // 64 KB (K=128) / 128 KB (K=256)

    const int tid = threadIdx.x;
    const int w = tid >> 6;
    const int l = tid & 63;
    const int lr = l & 15;
    const int lg = l >> 4;

    // cooperative load of all of W into LDS (linear copy, fragment-ordered)
#pragma unroll
    for (int i = 0; i < K / 16; ++i) {
        int o = (i * 512 + tid) * 8;
        *reinterpret_cast<uint4*>(&Wsh[o]) = *reinterpret_cast<const uint4*>(Wb + o);
    }
    __syncthreads();

    float bv[16];
#pragma unroll
    for (int nt = 0; nt < 16; ++nt) bv[nt] = bias[nt * 16 + lr];

    for (int t = blockIdx.x; t < N_TILES; t += 256) {
        const int rowbase = t * 256 + w * 32;
        int r0 = rowbase + lr;
        int r1 = rowbase + 16 + lr;
        int r0c = r0 < N_NODES ? r0 : (N_NODES - 1);
        int r1c = r1 < N_NODES ? r1 : (N_NODES - 1);
        const unsigned short* a0p = A + (size_t)r0c * K + lg * 8;
        const unsigned short* a1p = A + (size_t)r1c * K + lg * 8;

        bf16x8 a0[NK], a1[NK];
#pragma unroll
        for (int kc = 0; kc < NK; ++kc) {
            a0[kc] = *reinterpret_cast<const bf16x8*>(a0p + kc * 32);
            a1[kc] = *reinterpret_cast<const bf16x8*>(a1p + kc * 32);
        }

        f32x4 acc0[16] = {};
        f32x4 acc1[16] = {};

#pragma unroll
        for (int kc = 0; kc < NK; ++kc) {
            const unsigned short* bfp = Wsh + kc * 8192 + l * 8;
#pragma unroll
            for (int nt = 0; nt < 16; ++nt) {
                bf16x8 bb = *reinterpret_cast<const bf16x8*>(bfp + nt * 512);
                acc0[nt] = __builtin_amdgcn_mfma_f32_16x16x32_bf16(a0[kc], bb, acc0[nt], 0, 0, 0);
                acc1[nt] = __builtin_amdgcn_mfma_f32_16x16x32_bf16(a1[kc], bb, acc1[nt], 0, 0, 0);
            }
        }

        // C/D layout: col = lane&15, row = (lane>>4)*4 + j ; epilogue: +bias, relu
        int gr0 = rowbase + lg * 4;
#pragma unroll
        for (int j = 0; j < 4; ++j) {
            int gr = gr0 + j;
            if (gr < N_NODES) {
                size_t base = (size_t)gr * HID + lr;
#pragma unroll
                for (int nt = 0; nt < 16; ++nt)
                    Cb[base + nt * 16] = f2bf(fmaxf(acc0[nt][j] + bv[nt], 0.0f));
            }
            int gr2 = gr + 16;
            if (gr2 < N_NODES) {
                size_t base = (size_t)gr2 * HID + lr;
#pragma unroll
                for (int nt = 0; nt < 16; ++nt)
                    Cb[base + nt * 16] = f2bf(fmaxf(acc1[nt][j] + bv[nt], 0.0f));
            }
        }
    }
}

// ---------------- aggregate (pure linear): ob = bf16(dinv^2*in_self + sum norm*in[src]) ----------------
// 256-wide rows: one 64-lane wave per node, ushort4 per lane
__global__ void k_aggregate256(const unsigned short* __restrict__ tb,
                               const float* __restrict__ dinv, const int* __restrict__ off,
                               const int* __restrict__ cnt, const int* __restrict__ csr_src,
                               unsigned short* __restrict__ ob) {
    int node = blockIdx.x * 4 + (threadIdx.x >> 6);
    if (node >= N_NODES) return;
    int lane = threadIdx.x & 63;
    float di = dinv[node];
    float s2 = di * di;
    ushort4 sv = *reinterpret_cast<const ushort4*>(&tb[(size_t)node * HID + lane * 4]);
    float4 acc = {bf2f(sv.x) * s2, bf2f(sv.y) * s2, bf2f(sv.z) * s2, bf2f(sv.w) * s2};

    int o0 = off[node];
    int n = cnt[node];
    int j = 0;
    for (; j + 1 < n; j += 2) {
        int s0 = csr_src[o0 + j];
        int s1 = csr_src[o0 + j + 1];
        float n0 = dinv[s0] * di;
        float n1 = dinv[s1] * di;
        ushort4 u0 = *reinterpret_cast<const ushort4*>(&tb[(size_t)s0 * HID + lane * 4]);
        ushort4 u1 = *reinterpret_cast<const ushort4*>(&tb[(size_t)s1 * HID + lane * 4]);
        acc.x = fmaf(n0, bf2f(u0.x), acc.x);
        acc.y = fmaf(n0, bf2f(u0.y), acc.y);
        acc.z = fmaf(n0, bf2f(u0.z), acc.z);
        acc.w = fmaf(n0, bf2f(u0.w), acc.w);
        acc.x = fmaf(n1, bf2f(u1.x), acc.x);
        acc.y = fmaf(n1, bf2f(u1.y), acc.y);
        acc.z = fmaf(n1, bf2f(u1.z), acc.z);
        acc.w = fmaf(n1, bf2f(u1.w), acc.w);
    }
    if (j < n) {
        int s0 = csr_src[o0 + j];
        float n0 = dinv[s0] * di;
        ushort4 u0 = *reinterpret_cast<const ushort4*>(&tb[(size_t)s0 * HID + lane * 4]);
        acc.x = fmaf(n0, bf2f(u0.x), acc.x);
        acc.y = fmaf(n0, bf2f(u0.y), acc.y);
        acc.z = fmaf(n0, bf2f(u0.z), acc.z);
        acc.w = fmaf(n0, bf2f(u0.w), acc.w);
    }
    ushort4 o;
    o.x = f2bf(acc.x);
    o.y = f2bf(acc.y);
    o.z = f2bf(acc.z);
    o.w = f2bf(acc.w);
    *reinterpret_cast<ushort4*>(&ob[(size_t)node * HID + lane * 4]) = o;
}

// 128-wide rows: one 64-lane wave per node, ushort2 per lane
__global__ void k_aggregate128(const unsigned short* __restrict__ tb,
                               const float* __restrict__ dinv, const int* __restrict__ off,
                               const int* __restrict__ cnt, const int* __restrict__ csr_src,
                               unsigned short* __restrict__ ob) {
    int node = blockIdx.x * 4 + (threadIdx.x >> 6);
    if (node >= N_NODES) return;
    int lane = threadIdx.x & 63;
    float di = dinv[node];
    float s2 = di * di;
    ushort2 sv = *reinterpret_cast<const ushort2*>(&tb[(size_t)node * K1PAD + lane * 2]);
    float2 acc = {bf2f(sv.x) * s2, bf2f(sv.y) * s2};

    int o0 = off[node];
    int n = cnt[node];
    int j = 0;
    for (; j + 1 < n; j += 2) {
        int s0 = csr_src[o0 + j];
        int s1 = csr_src[o0 + j + 1];
        float n0 = dinv[s0] * di;
        float n1 = dinv[s1] * di;
        ushort2 u0 = *reinterpret_cast<const ushort2*>(&tb[(size_t)s0 * K1PAD + lane * 2]);
        ushort2 u1 = *reinterpret_cast<const ushort2*>(&tb[(size_t)s1 * K1PAD + lane * 2]);
        acc.x = fmaf(n0, bf2f(u0.x), acc.x);
        acc.y = fmaf(n0, bf2f(u0.y), acc.y);
        acc.x = fmaf(n1, bf2f(u1.x), acc.x);
        acc.y = fmaf(n1, bf2f(u1.y), acc.y);
    }
    if (j < n) {
        int s0 = csr_src[o0 + j];
        float n0 = dinv[s0] * di;
        ushort2 u0 = *reinterpret_cast<const ushort2*>(&tb[(size_t)s0 * K1PAD + lane * 2]);
        acc.x = fmaf(n0, bf2f(u0.x), acc.x);
        acc.y = fmaf(n0, bf2f(u0.y), acc.y);
    }
    ushort2 o;
    o.x = f2bf(acc.x);
    o.y = f2bf(acc.y);
    *reinterpret_cast<ushort2*>(&ob[(size_t)node * K1PAD + lane * 2]) = o;
}

// ---------------- pool: one wave per graph, contiguous rows, register max ----------------
__global__ void k_pool2(const unsigned short* __restrict__ hb, const int* __restrict__ gstart,
                        float* __restrict__ out) {
    int g = blockIdx.x;
    int lane = threadIdx.x;
    int s = gstart[g], e = gstart[g + 1];
    float4 m = {0.0f, 0.0f, 0.0f, 0.0f};  // h >= 0 after relu
    for (int i = s; i < e; ++i) {
        ushort4 u = *reinterpret_cast<const ushort4*>(&hb[(size_t)i * HID + lane * 4]);
        m.x = fmaxf(m.x, bf2f(u.x));
        m.y = fmaxf(m.y, bf2f(u.y));
        m.z = fmaxf(m.z, bf2f(u.z));
        m.w = fmaxf(m.w, bf2f(u.w));
    }
    *reinterpret_cast<float4*>(&out[(size_t)g * HID + lane * 4]) = m;
}

extern "C" void kernel_launch(void* const* d_in, const int* in_sizes, int n_in,
                              void* d_out, int out_size, void* d_ws, size_t ws_size,
                              hipStream_t stream) {
    const float* x = (const float*)d_in[0];
    const int* ei = (const int*)d_in[1];
    const int* batch = (const int*)d_in[2];
    const float* W1 = (const float*)d_in[4];
    const float* b1 = (const float*)d_in[5];
    const float* W2 = (const float*)d_in[6];
    const float* b2 = (const float*)d_in[7];
    const float* W3 = (const float*)d_in[8];
    const float* b3 = (const float*)d_in[9];
    float* out = (float*)d_out;

    // workspace layout (~158 MB)
    char* ws = (char*)d_ws;
    float* dinv = (float*)(ws);
    int* cnt = (int*)(ws + (512 << 10));
    int* off = (int*)(ws + (1024 << 10));
    int* cur = (int*)(ws + (1536 << 10));
    int* part = (int*)(ws + (2048 << 10));
    int* gstart = (int*)(ws + (2048 << 10) + 4096);
    int* csr_src = (int*)(ws + (2176 << 10));
    unsigned short* Wb1 = (unsigned short*)(ws + (3584 << 10));   // 64 KB
    unsigned short* Wb2 = (unsigned short*)(ws + (3712 << 10));   // 128 KB
    unsigned short* Wb3 = (unsigned short*)(ws + (3904 << 10));   // 128 KB
    unsigned short* x_b = (unsigned short*)(ws + (4096 << 10));                  // 25.6 MB
    unsigned short* ag1_b = (unsigned short*)(ws + (4096 << 10) + 25600000);     // 25.6 MB
    unsigned short* bufA = (unsigned short*)(ws + (4096 << 10) + 51200000);      // 51.2 MB
    unsigned short* bufB = (unsigned short*)(ws + (4096 << 10) + 102400000);     // 51.2 MB

    const int nblk_nodes = (N_NODES + 255) / 256;
    const int nblk_edges = (N_EDGES + 255) / 256;
    const int nblk_rows4 = (N_NODES + 3) / 4;

    // ---- CSR + dinv + graph bounds ----
    k_cnt_init<<<nblk_nodes, 256, 0, stream>>>(cnt);
    k_cnt_acc<<<nblk_edges, 256, 0, stream>>>(ei, cnt);
    k_scan1<<<NBLK_SCAN, 256, 0, stream>>>(cnt, off, part);
    k_scan2<<<1, 64, 0, stream>>>(part);
    k_scan3<<<nblk_nodes, 256, 0, stream>>>(off, part, cur, cnt, dinv);
    k_fill<<<nblk_edges, 256, 0, stream>>>(ei, cur, csr_src);
    k_bounds<<<(N_GRAPHS + 256) / 256, 256, 0, stream>>>(batch, gstart);

    // ---- bf16 conversions ----
    k_xconv<<<(N_NODES * K1PAD + 255) / 256, 256, 0, stream>>>(x, x_b);
    k_wconv<<<(256 * K1PAD + 255) / 256, 256, 0, stream>>>(W1, Wb1, K1PAD, INDIM);
    k_wconv<<<(256 * HID + 255) / 256, 256, 0, stream>>>(W2, Wb2, HID, HID);
    k_wconv<<<(256 * HID + 255) / 256, 256, 0, stream>>>(W3, Wb3, HID, HID);

    // ---- layer 1: agg-first (Âx)W1 ----
    k_aggregate128<<<nblk_rows4, 256, 0, stream>>>(x_b, dinv, off, cnt, csr_src, ag1_b);
    k_gemm_mfma<K1PAD><<<256, 512, 0, stream>>>(ag1_b, Wb1, b1, bufA);

    // ---- layer 2 ----
    k_aggregate256<<<nblk_rows4, 256, 0, stream>>>(bufA, dinv, off, cnt, csr_src, bufB);
    k_gemm_mfma<HID><<<256, 512, 0, stream>>>(bufB, Wb2, b2, bufA);

    // ---- layer 3 ----
    k_aggregate256<<<nblk_rows4, 256, 0, stream>>>(bufA, dinv, off, cnt, csr_src, bufB);
    k_gemm_mfma<HID><<<256, 512, 0, stream>>>(bufB, Wb3, b3, bufA);

    // ---- pool ----
    k_pool2<<<N_GRAPHS, 64, 0, stream>>>(bufA, gstart, out);
}

// Round 8
// 262.847 us; speedup vs baseline: 14.8507x; 1.0756x over previous
//
#include <hip/hip_runtime.h>
#include <cstdint>
#include <cstddef>

#define N_NODES 100000
#define N_EDGES 300000
#define N_GRAPHS 2000
#define HID 256
#define INDIM 82
#define K1PAD 128
#define N_TILES ((N_NODES + 255) / 256)  // 391
#define SCAN_CHUNK 2048
#define NBLK_SCAN ((N_NODES + SCAN_CHUNK - 1) / SCAN_CHUNK)  // 49

typedef __bf16 bf16x8 __attribute__((ext_vector_type(8)));
typedef float f32x4 __attribute__((ext_vector_type(4)));

__device__ __forceinline__ unsigned short f2bf(float f) {
    unsigned int u = __float_as_uint(f);
    u = (u + 0x7fffu + ((u >> 16) & 1u)) >> 16;  // RNE
    return (unsigned short)u;
}
__device__ __forceinline__ float bf2f(unsigned short s) {
    return __uint_as_float(((unsigned int)s) << 16);
}

// ---------------- degree counting ----------------
__global__ void k_cnt_init(int* cnt) {
    int i = blockIdx.x * 256 + threadIdx.x;
    if (i < N_NODES) cnt[i] = 0;
}

__global__ void k_cnt_acc(const int* __restrict__ ei, int* cnt) {
    int e = blockIdx.x * 256 + threadIdx.x;
    if (e < N_EDGES) atomicAdd(&cnt[ei[N_EDGES + e]], 1);
}

// ---------------- exclusive prefix sum ----------------
__global__ __launch_bounds__(256) void k_scan1(const int* __restrict__ cnt, int* __restrict__ off,
                                               int* __restrict__ partial) {
    __shared__ int sdata[256];
    const int base = blockIdx.x * SCAN_CHUNK;
    const int t = threadIdx.x;
    int v[8];
    int s = 0;
#pragma unroll
    for (int i = 0; i < 8; ++i) {
        int idx = base + t * 8 + i;
        v[i] = (idx < N_NODES) ? cnt[idx] : 0;
        s += v[i];
    }
    sdata[t] = s;
    __syncthreads();
    for (int d = 1; d < 256; d <<= 1) {
        int x = (t >= d) ? sdata[t - d] : 0;
        __syncthreads();
        sdata[t] += x;
        __syncthreads();
    }
    int run = sdata[t] - s;
#pragma unroll
    for (int i = 0; i < 8; ++i) {
        int idx = base + t * 8 + i;
        if (idx < N_NODES) off[idx] = run;
        run += v[i];
    }
    if (t == 255) partial[blockIdx.x] = sdata[255];
}

__global__ void k_scan2(int* partial) {
    if (threadIdx.x == 0 && blockIdx.x == 0) {
        int run = 0;
        for (int i = 0; i < NBLK_SCAN; ++i) {
            int v = partial[i];
            partial[i] = run;
            run += v;
        }
    }
}

// scan fixup + cur init + dinv (merged)
__global__ void k_scan3(int* __restrict__ off, const int* __restrict__ partial,
                        int* __restrict__ cur, const int* __restrict__ cnt,
                        float* __restrict__ dinv) {
    int i = blockIdx.x * 256 + threadIdx.x;
    if (i < N_NODES) {
        int o = off[i] + partial[i >> 11];
        off[i] = o;
        cur[i] = o;
        dinv[i] = rsqrtf((float)cnt[i] + 1.0f);
    }
}

// CSR fill with precomputed edge norm (kills the random dinv gather in the hot loop)
__global__ void k_fill(const int* __restrict__ ei, const float* __restrict__ dinv, int* cur,
                       int* __restrict__ csr_src, float* __restrict__ csr_norm) {
    int e = blockIdx.x * 256 + threadIdx.x;
    if (e < N_EDGES) {
        int s = ei[e];
        int d = ei[N_EDGES + e];
        int pos = atomicAdd(&cur[d], 1);
        csr_src[pos] = s;
        csr_norm[pos] = dinv[s] * dinv[d];
    }
}

// ---------------- graph boundaries (batch is sorted) ----------------
__global__ void k_bounds(const int* __restrict__ batch, int* __restrict__ gstart) {
    int g = blockIdx.x * 256 + threadIdx.x;
    if (g > N_GRAPHS) return;
    int lo = 0, hi = N_NODES;
    while (lo < hi) {
        int mid = (lo + hi) >> 1;
        if (batch[mid] < g) lo = mid + 1;
        else hi = mid;
    }
    gstart[g] = lo;
}

// W [KSRC][256] f32 -> Wb fragment-contiguous: [kc][nt][lg][lr][j]
// offset = kc*8192 + nt*512 + lg*128 + lr*8 + j ; holds W[kc*32+lg*8+j][nt*16+lr]
__global__ void k_wconv(const float* __restrict__ W, unsigned short* __restrict__ Wb,
                        int KPAD, int KSRC) {
    int i = blockIdx.x * 256 + threadIdx.x;
    if (i >= 256 * KPAD) return;
    int kc = i >> 13;
    int r = i & 8191;
    int nt = r >> 9;
    int r2 = r & 511;
    int lg = r2 >> 7;
    int lr = (r2 >> 3) & 15;
    int j = r2 & 7;
    int k = kc * 32 + lg * 8 + j;
    int n = nt * 16 + lr;
    Wb[i] = (k < KSRC) ? f2bf(W[(size_t)k * HID + n]) : (unsigned short)0;
}

// ---------------- MFMA GEMM: Cb[N,256] = relu(A_bf16[N,K] @ W_bf16[K,256] + bias) ----------------
// 512 threads = 8 waves x 32 rows = 256 rows/tile. Whole W in LDS (loaded once,
// one barrier); persistent grid of 256 blocks loops over tiles; barrier-free K-loop.
template <int K>
__global__ __launch_bounds__(512) void k_gemm_mfma(const unsigned short* __restrict__ A,
                                                   const unsigned short* __restrict__ Wb,
                                                   const float* __restrict__ bias,
                                                   unsigned short* __restrict__ Cb) {
    constexpr int NK = K / 32;
    __shared__ __align__(16) unsigned short Wsh[K * HID];  // 64 KB (K=128) / 128 KB (K=256)

    const int tid = threadIdx.x;
    const int w = tid >> 6;
    const int l = tid & 63;
    const int lr = l & 15;
    const int lg = l >> 4;

    // cooperative load of all of W into LDS (linear copy, fragment-ordered)
#pragma unroll
    for (int i = 0; i < K / 16; ++i) {
        int o = (i * 512 + tid) * 8;
        *reinterpret_cast<uint4*>(&Wsh[o]) = *reinterpret_cast<const uint4*>(Wb + o);
    }
    __syncthreads();

    float bv[16];
#pragma unroll
    for (int nt = 0; nt < 16; ++nt) bv[nt] = bias[nt * 16 + lr];

    for (int t = blockIdx.x; t < N_TILES; t += 256) {
        const int rowbase = t * 256 + w * 32;
        int r0 = rowbase + lr;
        int r1 = rowbase + 16 + lr;
        int r0c = r0 < N_NODES ? r0 : (N_NODES - 1);
        int r1c = r1 < N_NODES ? r1 : (N_NODES - 1);
        const unsigned short* a0p = A + (size_t)r0c * K + lg * 8;
        const unsigned short* a1p = A + (size_t)r1c * K + lg * 8;

        bf16x8 a0[NK], a1[NK];
#pragma unroll
        for (int kc = 0; kc < NK; ++kc) {
            a0[kc] = *reinterpret_cast<const bf16x8*>(a0p + kc * 32);
            a1[kc] = *reinterpret_cast<const bf16x8*>(a1p + kc * 32);
        }

        f32x4 acc0[16] = {};
        f32x4 acc1[16] = {};

#pragma unroll
        for (int kc = 0; kc < NK; ++kc) {
            const unsigned short* bfp = Wsh + kc * 8192 + l * 8;
#pragma unroll
            for (int nt = 0; nt < 16; ++nt) {
                bf16x8 bb = *reinterpret_cast<const bf16x8*>(bfp + nt * 512);
                acc0[nt] = __builtin_amdgcn_mfma_f32_16x16x32_bf16(a0[kc], bb, acc0[nt], 0, 0, 0);
                acc1[nt] = __builtin_amdgcn_mfma_f32_16x16x32_bf16(a1[kc], bb, acc1[nt], 0, 0, 0);
            }
        }

        // C/D layout: col = lane&15, row = (lane>>4)*4 + j ; epilogue: +bias, relu
        int gr0 = rowbase + lg * 4;
#pragma unroll
        for (int j = 0; j < 4; ++j) {
            int gr = gr0 + j;
            if (gr < N_NODES) {
                size_t base = (size_t)gr * HID + lr;
#pragma unroll
                for (int nt = 0; nt < 16; ++nt)
                    Cb[base + nt * 16] = f2bf(fmaxf(acc0[nt][j] + bv[nt], 0.0f));
            }
            int gr2 = gr + 16;
            if (gr2 < N_NODES) {
                size_t base = (size_t)gr2 * HID + lr;
#pragma unroll
                for (int nt = 0; nt < 16; ++nt)
                    Cb[base + nt * 16] = f2bf(fmaxf(acc1[nt][j] + bv[nt], 0.0f));
            }
        }
    }
}

// ---------------- aggregate (pure linear): ob = bf16(dinv^2*in_self + sum norm*in[src]) ----------------
// 256-wide rows: one 64-lane wave per node, ushort4 per lane; 4-wide gather batching.
__global__ void k_aggregate256(const unsigned short* __restrict__ tb,
                               const float* __restrict__ dinv, const int* __restrict__ off,
                               const int* __restrict__ cnt, const int* __restrict__ csr_src,
                               const float* __restrict__ csr_norm,
                               unsigned short* __restrict__ ob) {
    int node = blockIdx.x * 4 + (threadIdx.x >> 6);
    if (node >= N_NODES) return;
    int lane = threadIdx.x & 63;
    const size_t lo = (size_t)lane * 4;
    int o0 = off[node];
    int n = cnt[node];
    float di = dinv[node];
    float s2 = di * di;
    ushort4 sv = *reinterpret_cast<const ushort4*>(&tb[(size_t)node * HID + lo]);
    float4 acc = {bf2f(sv.x) * s2, bf2f(sv.y) * s2, bf2f(sv.z) * s2, bf2f(sv.w) * s2};

    int j = 0;
    for (; j + 3 < n; j += 4) {
        int s0 = csr_src[o0 + j];
        int s1 = csr_src[o0 + j + 1];
        int s2i = csr_src[o0 + j + 2];
        int s3 = csr_src[o0 + j + 3];
        float n0 = csr_norm[o0 + j];
        float n1 = csr_norm[o0 + j + 1];
        float n2 = csr_norm[o0 + j + 2];
        float n3 = csr_norm[o0 + j + 3];
        ushort4 u0 = *reinterpret_cast<const ushort4*>(&tb[(size_t)s0 * HID + lo]);
        ushort4 u1 = *reinterpret_cast<const ushort4*>(&tb[(size_t)s1 * HID + lo]);
        ushort4 u2 = *reinterpret_cast<const ushort4*>(&tb[(size_t)s2i * HID + lo]);
        ushort4 u3 = *reinterpret_cast<const ushort4*>(&tb[(size_t)s3 * HID + lo]);
        acc.x = fmaf(n0, bf2f(u0.x), acc.x); acc.y = fmaf(n0, bf2f(u0.y), acc.y);
        acc.z = fmaf(n0, bf2f(u0.z), acc.z); acc.w = fmaf(n0, bf2f(u0.w), acc.w);
        acc.x = fmaf(n1, bf2f(u1.x), acc.x); acc.y = fmaf(n1, bf2f(u1.y), acc.y);
        acc.z = fmaf(n1, bf2f(u1.z), acc.z); acc.w = fmaf(n1, bf2f(u1.w), acc.w);
        acc.x = fmaf(n2, bf2f(u2.x), acc.x); acc.y = fmaf(n2, bf2f(u2.y), acc.y);
        acc.z = fmaf(n2, bf2f(u2.z), acc.z); acc.w = fmaf(n2, bf2f(u2.w), acc.w);
        acc.x = fmaf(n3, bf2f(u3.x), acc.x); acc.y = fmaf(n3, bf2f(u3.y), acc.y);
        acc.z = fmaf(n3, bf2f(u3.z), acc.z); acc.w = fmaf(n3, bf2f(u3.w), acc.w);
    }
    int rem = n - j;
    if (rem & 2) {
        int s0 = csr_src[o0 + j];
        int s1 = csr_src[o0 + j + 1];
        float n0 = csr_norm[o0 + j];
        float n1 = csr_norm[o0 + j + 1];
        ushort4 u0 = *reinterpret_cast<const ushort4*>(&tb[(size_t)s0 * HID + lo]);
        ushort4 u1 = *reinterpret_cast<const ushort4*>(&tb[(size_t)s1 * HID + lo]);
        acc.x = fmaf(n0, bf2f(u0.x), acc.x); acc.y = fmaf(n0, bf2f(u0.y), acc.y);
        acc.z = fmaf(n0, bf2f(u0.z), acc.z); acc.w = fmaf(n0, bf2f(u0.w), acc.w);
        acc.x = fmaf(n1, bf2f(u1.x), acc.x); acc.y = fmaf(n1, bf2f(u1.y), acc.y);
        acc.z = fmaf(n1, bf2f(u1.z), acc.z); acc.w = fmaf(n1, bf2f(u1.w), acc.w);
        j += 2;
    }
    if (rem & 1) {
        int s0 = csr_src[o0 + j];
        float n0 = csr_norm[o0 + j];
        ushort4 u0 = *reinterpret_cast<const ushort4*>(&tb[(size_t)s0 * HID + lo]);
        acc.x = fmaf(n0, bf2f(u0.x), acc.x); acc.y = fmaf(n0, bf2f(u0.y), acc.y);
        acc.z = fmaf(n0, bf2f(u0.z), acc.z); acc.w = fmaf(n0, bf2f(u0.w), acc.w);
    }
    ushort4 o;
    o.x = f2bf(acc.x);
    o.y = f2bf(acc.y);
    o.z = f2bf(acc.z);
    o.w = f2bf(acc.w);
    *reinterpret_cast<ushort4*>(&ob[(size_t)node * HID + lo]) = o;
}

// layer-1 fused: aggregate directly from f32 x [N,82], emit bf16 padded [N,128]
__global__ void k_aggxf(const float* __restrict__ x,
                        const float* __restrict__ dinv, const int* __restrict__ off,
                        const int* __restrict__ cnt, const int* __restrict__ csr_src,
                        const float* __restrict__ csr_norm,
                        unsigned short* __restrict__ ob) {
    int node = blockIdx.x * 4 + (threadIdx.x >> 6);
    if (node >= N_NODES) return;
    int lane = threadIdx.x & 63;
    const bool act = lane < 41;  // 2*41 = 82 = INDIM
    const size_t co = (size_t)lane * 2;
    int o0 = off[node];
    int n = cnt[node];
    float di = dinv[node];
    float s2 = di * di;
    float2 acc = {0.0f, 0.0f};
    if (act) {
        float2 sv = *reinterpret_cast<const float2*>(&x[(size_t)node * INDIM + co]);
        acc.x = sv.x * s2;
        acc.y = sv.y * s2;
        int j = 0;
        for (; j + 1 < n; j += 2) {
            int s0 = csr_src[o0 + j];
            int s1 = csr_src[o0 + j + 1];
            float n0 = csr_norm[o0 + j];
            float n1 = csr_norm[o0 + j + 1];
            float2 u0 = *reinterpret_cast<const float2*>(&x[(size_t)s0 * INDIM + co]);
            float2 u1 = *reinterpret_cast<const float2*>(&x[(size_t)s1 * INDIM + co]);
            acc.x = fmaf(n0, u0.x, acc.x); acc.y = fmaf(n0, u0.y, acc.y);
            acc.x = fmaf(n1, u1.x, acc.x); acc.y = fmaf(n1, u1.y, acc.y);
        }
        if (j < n) {
            int s0 = csr_src[o0 + j];
            float n0 = csr_norm[o0 + j];
            float2 u0 = *reinterpret_cast<const float2*>(&x[(size_t)s0 * INDIM + co]);
            acc.x = fmaf(n0, u0.x, acc.x); acc.y = fmaf(n0, u0.y, acc.y);
        }
    }
    ushort2 o;
    o.x = f2bf(acc.x);
    o.y = f2bf(acc.y);
    *reinterpret_cast<ushort2*>(&ob[(size_t)node * K1PAD + co]) = o;
}

// ---------------- pool: 2 waves per graph (column halves), contiguous rows ----------------
__global__ void k_pool2(const unsigned short* __restrict__ hb, const int* __restrict__ gstart,
                        float* __restrict__ out) {
    int g = blockIdx.x;
    int w = threadIdx.x >> 6;
    int lane = threadIdx.x & 63;
    int col = w * 128 + lane * 2;
    int s = gstart[g], e = gstart[g + 1];
    float2 m = {0.0f, 0.0f};  // h >= 0 after relu
    for (int i = s; i < e; ++i) {
        ushort2 u = *reinterpret_cast<const ushort2*>(&hb[(size_t)i * HID + col]);
        m.x = fmaxf(m.x, bf2f(u.x));
        m.y = fmaxf(m.y, bf2f(u.y));
    }
    *reinterpret_cast<float2*>(&out[(size_t)g * HID + col]) = m;
}

extern "C" void kernel_launch(void* const* d_in, const int* in_sizes, int n_in,
                              void* d_out, int out_size, void* d_ws, size_t ws_size,
                              hipStream_t stream) {
    const float* x = (const float*)d_in[0];
    const int* ei = (const int*)d_in[1];
    const int* batch = (const int*)d_in[2];
    const float* W1 = (const float*)d_in[4];
    const float* b1 = (const float*)d_in[5];
    const float* W2 = (const float*)d_in[6];
    const float* b2 = (const float*)d_in[7];
    const float* W3 = (const float*)d_in[8];
    const float* b3 = (const float*)d_in[9];
    float* out = (float*)d_out;

    // workspace layout (~133 MB)
    char* ws = (char*)d_ws;
    float* dinv = (float*)(ws);
    int* cnt = (int*)(ws + (512 << 10));
    int* off = (int*)(ws + (1024 << 10));
    int* cur = (int*)(ws + (1536 << 10));
    int* part = (int*)(ws + (2048 << 10));
    int* gstart = (int*)(ws + (2048 << 10) + 4096);
    int* csr_src = (int*)(ws + (2176 << 10));        // 1.2 MB
    float* csr_norm = (float*)(ws + (3392 << 10));   // 1.2 MB
    unsigned short* Wb1 = (unsigned short*)(ws + (4608 << 10));   // 64 KB
    unsigned short* Wb2 = (unsigned short*)(ws + (4736 << 10));   // 128 KB
    unsigned short* Wb3 = (unsigned short*)(ws + (4928 << 10));   // 128 KB
    unsigned short* ag1_b = (unsigned short*)(ws + (5120 << 10));               // 25.6 MB
    unsigned short* bufA = (unsigned short*)(ws + (5120 << 10) + 25600000);     // 51.2 MB
    unsigned short* bufB = (unsigned short*)(ws + (5120 << 10) + 76800000);     // 51.2 MB

    const int nblk_nodes = (N_NODES + 255) / 256;
    const int nblk_edges = (N_EDGES + 255) / 256;
    const int nblk_rows4 = (N_NODES + 3) / 4;

    // ---- CSR + dinv + graph bounds ----
    k_cnt_init<<<nblk_nodes, 256, 0, stream>>>(cnt);
    k_cnt_acc<<<nblk_edges, 256, 0, stream>>>(ei, cnt);
    k_scan1<<<NBLK_SCAN, 256, 0, stream>>>(cnt, off, part);
    k_scan2<<<1, 64, 0, stream>>>(part);
    k_scan3<<<nblk_nodes, 256, 0, stream>>>(off, part, cur, cnt, dinv);
    k_fill<<<nblk_edges, 256, 0, stream>>>(ei, dinv, cur, csr_src, csr_norm);
    k_bounds<<<(N_GRAPHS + 256) / 256, 256, 0, stream>>>(batch, gstart);

    // ---- weight conversions ----
    k_wconv<<<(256 * K1PAD + 255) / 256, 256, 0, stream>>>(W1, Wb1, K1PAD, INDIM);
    k_wconv<<<(256 * HID + 255) / 256, 256, 0, stream>>>(W2, Wb2, HID, HID);
    k_wconv<<<(256 * HID + 255) / 256, 256, 0, stream>>>(W3, Wb3, HID, HID);

    // ---- layer 1: agg-first (Âx)W1, aggregate fused with f32->bf16 ----
    k_aggxf<<<nblk_rows4, 256, 0, stream>>>(x, dinv, off, cnt, csr_src, csr_norm, ag1_b);
    k_gemm_mfma<K1PAD><<<256, 512, 0, stream>>>(ag1_b, Wb1, b1, bufA);

    // ---- layer 2 ----
    k_aggregate256<<<nblk_rows4, 256, 0, stream>>>(bufA, dinv, off, cnt, csr_src, csr_norm, bufB);
    k_gemm_mfma<HID><<<256, 512, 0, stream>>>(bufB, Wb2, b2, bufA);

    // ---- layer 3 ----
    k_aggregate256<<<nblk_rows4, 256, 0, stream>>>(bufA, dinv, off, cnt, csr_src, csr_norm, bufB);
    k_gemm_mfma<HID><<<256, 512, 0, stream>>>(bufB, Wb3, b3, bufA);

    // ---- pool ----
    k_pool2<<<N_GRAPHS, 128, 0, stream>>>(bufA, gstart, out);
}